// Round 2
// baseline (2055.945 us; speedup 1.0000x reference)
//
#include <hip/hip_runtime.h>
#include <cstdint>
#include <cstddef>

#define NN 20000
#define NE 320000
#define NG 256

typedef unsigned short u16;

// ---------------- bf16 helpers (storage bf16, math fp32) ----------------
__device__ inline float b2f(u16 h){
  union { unsigned u; float f; } v; v.u = ((unsigned)h) << 16; return v.f;
}
__device__ inline u16 f2b(float f){
  union { float f; unsigned u; } v; v.f = f;
  unsigned r = v.u + 0x7FFFu + ((v.u >> 16) & 1u);   // round-nearest-even
  return (u16)(r >> 16);
}
__device__ inline void up2(unsigned u, float& a, float& b){
  union { unsigned u; float f; } x, y;
  x.u = u << 16; y.u = u & 0xffff0000u;
  a = x.f; b = y.f;
}
__device__ inline unsigned pk2(float a, float b){
  return (unsigned)f2b(a) | (((unsigned)f2b(b)) << 16);
}

// ---------------- utility kernels ----------------

__global__ void k_zero(int* __restrict__ p, int n){
  int i = blockIdx.x*blockDim.x + threadIdx.x;
  if (i < n) p[i] = 0;
}

__global__ void k_deg(const int* __restrict__ ei, int* __restrict__ deg){
  int e = blockIdx.x*blockDim.x + threadIdx.x;
  if (e < NE) atomicAdd(&deg[ei[NE + e]], 1);   // dst = ei[1][e]
}

__global__ void k_dinv(const int* __restrict__ deg, float* __restrict__ dinv){
  int i = blockIdx.x*blockDim.x + threadIdx.x;
  if (i < NN) dinv[i] = rsqrtf(1.0f + (float)deg[i]);
}

// single-block exclusive scan of counts[NN] -> offs[NN+1]
__global__ void k_scan(const int* __restrict__ counts, int* __restrict__ offs){
  __shared__ int sm[1024];
  int tid = threadIdx.x;
  int carry = 0;
  for (int base = 0; base < NN; base += 1024){
    int idx = base + tid;
    int v = (idx < NN) ? counts[idx] : 0;
    sm[tid] = v;
    __syncthreads();
    for (int d = 1; d < 1024; d <<= 1){
      int t = (tid >= d) ? sm[tid - d] : 0;
      __syncthreads();
      sm[tid] += t;
      __syncthreads();
    }
    int incl = sm[tid];
    if (idx < NN) offs[idx] = carry + incl - v;
    int total = sm[1023];
    __syncthreads();
    carry += total;
  }
  if (tid == 0) offs[NN] = carry;
}

__global__ void k_fill(const int* __restrict__ ei, const int* __restrict__ offs,
                       int* __restrict__ cur, int* __restrict__ srcs){
  int e = blockIdx.x*blockDim.x + threadIdx.x;
  if (e < NE){
    int s = ei[e];
    int d = ei[NE + e];
    int p = atomicAdd(&cur[d], 1);
    srcs[offs[d] + p] = s;
  }
}

__global__ void k_bounds(const int* __restrict__ batch, int* __restrict__ start){
  int i = blockIdx.x*blockDim.x + threadIdx.x;
  if (i < NN){
    int b  = batch[i];
    int bp = (i == 0) ? -1 : batch[i-1];
    for (int g = bp + 1; g <= b; g++) start[g] = i;
    if (i == NN - 1){
      for (int g = b + 1; g <= NG; g++) start[g] = NN;
    }
  }
}

// cast fp32 x -> bf16 (4 elems/thread)
__global__ void k_cast(const float4* __restrict__ x, ushort4* __restrict__ xb, int total4){
  int t = blockIdx.x*blockDim.x + threadIdx.x;
  if (t >= total4) return;
  float4 v = x[t];
  ushort4 o; o.x = f2b(v.x); o.y = f2b(v.y); o.z = f2b(v.z); o.w = f2b(v.w);
  xb[t] = o;
}

// ---------------- aggregation (bf16 in/out, fp32 accumulate) ----------------
// out[i] = dinv[i] * ( dinv[i]*in[i] + sum_{j in nbr(i)} dinv[j]*in[j] )
// 8 channels per thread (one uint4 = 8 bf16)
template<int C8>
__global__ void k_agg_b(const uint4* __restrict__ in, uint4* __restrict__ out,
                        const float* __restrict__ dinv, const int* __restrict__ offs,
                        const int* __restrict__ srcs){
  int t = blockIdx.x*blockDim.x + threadIdx.x;
  if (t >= NN * C8) return;
  int i = t / C8;
  int c = t - i * C8;
  float di = dinv[i];
  float a[8], acc[8];
  uint4 xv = in[t];
  up2(xv.x, a[0], a[1]); up2(xv.y, a[2], a[3]);
  up2(xv.z, a[4], a[5]); up2(xv.w, a[6], a[7]);
  #pragma unroll
  for (int k = 0; k < 8; k++) acc[k] = a[k] * di;
  int e1 = offs[i + 1];
  for (int e = offs[i]; e < e1; e++){
    int s = srcs[e];
    float ds = dinv[s];
    uint4 yv = in[(size_t)s * C8 + c];
    up2(yv.x, a[0], a[1]); up2(yv.y, a[2], a[3]);
    up2(yv.z, a[4], a[5]); up2(yv.w, a[6], a[7]);
    #pragma unroll
    for (int k = 0; k < 8; k++) acc[k] = fmaf(a[k], ds, acc[k]);
  }
  #pragma unroll
  for (int k = 0; k < 8; k++) acc[k] *= di;
  uint4 o;
  o.x = pk2(acc[0], acc[1]); o.y = pk2(acc[2], acc[3]);
  o.z = pk2(acc[4], acc[5]); o.w = pk2(acc[6], acc[7]);
  out[t] = o;
}

// ---------------- GEMM, A bf16 [M,K], B fp32 [K,Nc], C bf16 [M,Nc] ----------------
// MODE: 0 = bias, 1 = bias+relu, 2 = bias + add-into-existing-C
template<int MODE>
__global__ __launch_bounds__(256) void k_gemm_b(const u16* __restrict__ A,
                                                const float* __restrict__ B,
                                                const float* __restrict__ bias,
                                                u16* __restrict__ C,
                                                int M, int K, int Nc){
  __shared__ float As[16][68];
  __shared__ float Bs[16][64];
  const int tid = threadIdx.x;
  const int tx = tid & 15, ty = tid >> 4;
  const int bm = blockIdx.x * 64, bn = blockIdx.y * 64;
  const int arow = tid >> 2, akq = (tid & 3) << 2;
  const int brow = tid >> 4, bcol = (tid & 15) << 2;
  float acc[4][4] = {{0.f}};
  const bool aval = (bm + arow) < M;
  const u16* Aptr = A + (size_t)(bm + arow) * K + akq;
  const float* Bptr = B + (size_t)brow * Nc + bn + bcol;
  for (int k0 = 0; k0 < K; k0 += 16){
    ushort4 av = make_ushort4(0,0,0,0);
    if (aval) av = *(const ushort4*)(Aptr + k0);
    float4 bv = *(const float4*)(Bptr + (size_t)k0 * Nc);
    As[akq + 0][arow] = b2f(av.x);
    As[akq + 1][arow] = b2f(av.y);
    As[akq + 2][arow] = b2f(av.z);
    As[akq + 3][arow] = b2f(av.w);
    *(float4*)&Bs[brow][bcol] = bv;
    __syncthreads();
    #pragma unroll
    for (int kk = 0; kk < 16; kk++){
      const float4 a = *(const float4*)(&As[kk][ty << 2]);
      const float4 b = *(const float4*)(&Bs[kk][tx << 2]);
      const float ar[4] = {a.x, a.y, a.z, a.w};
      const float br[4] = {b.x, b.y, b.z, b.w};
      #pragma unroll
      for (int i = 0; i < 4; i++)
        #pragma unroll
        for (int j = 0; j < 4; j++)
          acc[i][j] = fmaf(ar[i], br[j], acc[i][j]);
    }
    __syncthreads();
  }
  const int col = bn + (tx << 2);
  const float4 bb = *(const float4*)(bias + col);
  #pragma unroll
  for (int i = 0; i < 4; i++){
    int row = bm + (ty << 2) + i;
    if (row < M){
      float o0 = acc[i][0] + bb.x;
      float o1 = acc[i][1] + bb.y;
      float o2 = acc[i][2] + bb.z;
      float o3 = acc[i][3] + bb.w;
      if (MODE == 1){
        o0 = fmaxf(o0, 0.f); o1 = fmaxf(o1, 0.f);
        o2 = fmaxf(o2, 0.f); o3 = fmaxf(o3, 0.f);
      }
      u16* cp = C + (size_t)row * Nc + col;
      if (MODE == 2){
        ushort4 old = *(const ushort4*)cp;
        o0 += b2f(old.x); o1 += b2f(old.y); o2 += b2f(old.z); o3 += b2f(old.w);
      }
      ushort4 ov; ov.x = f2b(o0); ov.y = f2b(o1); ov.z = f2b(o2); ov.w = f2b(o3);
      *(ushort4*)cp = ov;
    }
  }
}

// ---------------- fp32 GEMM (MLP tail, small M) ----------------
template<bool RELU>
__global__ __launch_bounds__(256) void k_gemm(const float* __restrict__ A,
                                              const float* __restrict__ B,
                                              const float* __restrict__ bias,
                                              float* __restrict__ C,
                                              int M, int K, int Nc){
  __shared__ float As[16][68];
  __shared__ float Bs[16][64];
  const int tid = threadIdx.x;
  const int tx = tid & 15, ty = tid >> 4;
  const int bm = blockIdx.x * 64, bn = blockIdx.y * 64;
  const int arow = tid >> 2, akq = (tid & 3) << 2;
  const int brow = tid >> 4, bcol = (tid & 15) << 2;
  float acc[4][4] = {{0.f}};
  const bool aval = (bm + arow) < M;
  const float* Aptr = A + (size_t)(bm + arow) * K + akq;
  const float* Bptr = B + (size_t)brow * Nc + bn + bcol;
  for (int k0 = 0; k0 < K; k0 += 16){
    float4 av = make_float4(0.f, 0.f, 0.f, 0.f);
    if (aval) av = *(const float4*)(Aptr + k0);
    float4 bv = *(const float4*)(Bptr + (size_t)k0 * Nc);
    As[akq + 0][arow] = av.x;
    As[akq + 1][arow] = av.y;
    As[akq + 2][arow] = av.z;
    As[akq + 3][arow] = av.w;
    *(float4*)&Bs[brow][bcol] = bv;
    __syncthreads();
    #pragma unroll
    for (int kk = 0; kk < 16; kk++){
      const float4 a = *(const float4*)(&As[kk][ty << 2]);
      const float4 b = *(const float4*)(&Bs[kk][tx << 2]);
      const float ar[4] = {a.x, a.y, a.z, a.w};
      const float br[4] = {b.x, b.y, b.z, b.w};
      #pragma unroll
      for (int i = 0; i < 4; i++)
        #pragma unroll
        for (int j = 0; j < 4; j++)
          acc[i][j] = fmaf(ar[i], br[j], acc[i][j]);
    }
    __syncthreads();
  }
  const int col = bn + (tx << 2);
  const float4 bb = *(const float4*)(bias + col);
  #pragma unroll
  for (int i = 0; i < 4; i++){
    int row = bm + (ty << 2) + i;
    if (row < M){
      float4 o;
      o.x = acc[i][0] + bb.x;
      o.y = acc[i][1] + bb.y;
      o.z = acc[i][2] + bb.z;
      o.w = acc[i][3] + bb.w;
      if (RELU){
        o.x = fmaxf(o.x, 0.f); o.y = fmaxf(o.y, 0.f);
        o.z = fmaxf(o.z, 0.f); o.w = fmaxf(o.w, 0.f);
      }
      *(float4*)(C + (size_t)row * Nc + col) = o;
    }
  }
}

// ---------------- BatchNorm (bf16 raw, fp32 stats) ----------------

__global__ void k_bnstats_b(const u16* __restrict__ h, float* __restrict__ sacc,
                            float* __restrict__ s2acc, int C){
  int c = blockIdx.x * blockDim.x + threadIdx.x;
  if (c >= C) return;
  int sl = blockIdx.y, nsl = gridDim.y;
  int r0 = (int)(((long long)NN * sl) / nsl);
  int r1 = (int)(((long long)NN * (sl + 1)) / nsl);
  float s = 0.f, s2 = 0.f;
  for (int r = r0; r < r1; r++){
    float v = b2f(h[(size_t)r * C + c]);
    s += v; s2 += v * v;
  }
  atomicAdd(&sacc[c], s);
  atomicAdd(&s2acc[c], s2);
}

__global__ void k_bnfin(const float* __restrict__ sacc, const float* __restrict__ s2acc,
                        const float* __restrict__ g, const float* __restrict__ be,
                        float* __restrict__ scale, float* __restrict__ shift, int C){
  int c = blockIdx.x * blockDim.x + threadIdx.x;
  if (c >= C) return;
  float m = sacc[c] * (1.0f / NN);
  float v = s2acc[c] * (1.0f / NN) - m * m;
  float rs = rsqrtf(v + 1e-5f);
  float sc = g[c] * rs;
  scale[c] = sc;
  shift[c] = be[c] - m * sc;
}

// out = relu(raw*scale + shift), bf16 in/out, 4 elems/thread
__global__ void k_bnapply_b(const ushort4* __restrict__ raw, const float* __restrict__ scale,
                            const float* __restrict__ shift, ushort4* __restrict__ out,
                            int C4, int total){
  int t = blockIdx.x * blockDim.x + threadIdx.x;
  if (t >= total) return;
  int c4 = t % C4;
  ushort4 v = raw[t];
  float4 sc = ((const float4*)scale)[c4];
  float4 sh = ((const float4*)shift)[c4];
  float r0 = fmaxf(fmaf(b2f(v.x), sc.x, sh.x), 0.f);
  float r1 = fmaxf(fmaf(b2f(v.y), sc.y, sh.y), 0.f);
  float r2 = fmaxf(fmaf(b2f(v.z), sc.z, sh.z), 0.f);
  float r3 = fmaxf(fmaf(b2f(v.w), sc.w, sh.w), 0.f);
  ushort4 o; o.x = f2b(r0); o.y = f2b(r1); o.z = f2b(r2); o.w = f2b(r3);
  out[t] = o;
}

// ---------------- mean pool: h2 bf16 [NN,1024] -> pooled fp32 [NG,1024] ----------------
__global__ void k_pool_b(const u16* __restrict__ h, const int* __restrict__ start,
                         float* __restrict__ pooled){
  int g = blockIdx.x;
  int c = threadIdx.x << 2;   // 0..1020
  int r0 = start[g], r1 = start[g + 1];
  float a0 = 0.f, a1 = 0.f, a2 = 0.f, a3 = 0.f;
  for (int r = r0; r < r1; r++){
    ushort4 v = *(const ushort4*)(h + (size_t)r * 1024 + c);
    a0 += b2f(v.x); a1 += b2f(v.y); a2 += b2f(v.z); a3 += b2f(v.w);
  }
  float inv = (r1 > r0) ? (1.0f / (float)(r1 - r0)) : 0.0f;
  float4 o; o.x = a0 * inv; o.y = a1 * inv; o.z = a2 * inv; o.w = a3 * inv;
  *(float4*)(pooled + (size_t)g * 1024 + c) = o;
}

// ---------------- host launcher ----------------

extern "C" void kernel_launch(void* const* d_in, const int* in_sizes, int n_in,
                              void* d_out, int out_size, void* d_ws, size_t ws_size,
                              hipStream_t stream) {
  const float* x    = (const float*)d_in[0];
  const int*   ei   = (const int*)d_in[1];
  const int*   bat  = (const int*)d_in[2];
  const float* w0   = (const float*)d_in[3];
  const float* b0   = (const float*)d_in[4];
  const float* a_w1 = (const float*)d_in[5],  *a_b1  = (const float*)d_in[6];
  const float* a_g1 = (const float*)d_in[7],  *a_be1 = (const float*)d_in[8];
  const float* a_w2 = (const float*)d_in[9],  *a_b2  = (const float*)d_in[10];
  const float* a_g2 = (const float*)d_in[11], *a_be2 = (const float*)d_in[12];
  const float* a_w3 = (const float*)d_in[13], *a_b3  = (const float*)d_in[14];
  const float* c_w1 = (const float*)d_in[15], *c_b1  = (const float*)d_in[16];
  const float* c_g1 = (const float*)d_in[17], *c_be1 = (const float*)d_in[18];
  const float* c_w2 = (const float*)d_in[19], *c_b2  = (const float*)d_in[20];
  const float* c_g2 = (const float*)d_in[21], *c_be2 = (const float*)d_in[22];
  const float* c_w3 = (const float*)d_in[23], *c_b3  = (const float*)d_in[24];
  const float* mw1  = (const float*)d_in[25], *mb1   = (const float*)d_in[26];
  const float* mw2  = (const float*)d_in[27], *mb2   = (const float*)d_in[28];
  float* out = (float*)d_out;

  char* pp = (char*)d_ws;
  auto alloc = [&](size_t b)->char*{ char* r = pp; pp += (b + 255) & ~(size_t)255; return r; };

  // single bf16 activation region, hand-scheduled. 1 channel-slot = NN*2 bytes.
  const size_t CH = (size_t)NN * 2;
  char* R = alloc(2304 * CH);                      // 92.16 MB
  float* dinv = (float*)alloc((size_t)NN * 4);
  int* deg    = (int*)alloc((size_t)NN * 4);
  int* offs   = (int*)alloc((size_t)(NN + 1) * 4);
  int* cur    = (int*)alloc((size_t)NN * 4);
  int* srcs   = (int*)alloc((size_t)NE * 4);
  int* startg = (int*)alloc((size_t)(NG + 1) * 4);
  float* sacc = (float*)alloc(2048 * 4);
  float* s2acc = sacc + 1024;
  float* scv  = (float*)alloc(1024 * 4);
  float* shv  = (float*)alloc(1024 * 4);
  float* P    = (float*)alloc((size_t)NG * 1024 * 4);
  float* Hh   = (float*)alloc((size_t)NG * 1024 * 4);
  // total ~96 MB

  // liveness-scheduled channel offsets
  u16* xb  = (u16*)(R + 0    * CH);   // [128]  dead after ax
  u16* ax  = (u16*)(R + 128  * CH);   // [128]  dead after h0
  u16* h0  = (u16*)(R + 256  * CH);   // [256]  dead after ah0
  u16* ah0 = (u16*)(R + 512  * CH);   // [256]  live until skip gemm_add
  u16* t1  = (u16*)(R + 768  * CH);   // [384]  t1raw/t1, dead after at
  u16* at  = (u16*)(R + 1152 * CH);   // [384]  dead after t2raw
  u16* h1  = (u16*)(R + 0    * CH);   // [512]  t2raw/h1 (overwrites dead xb/ax/h0 prefix)
  u16* ah1 = (u16*)(R + 1792 * CH);   // [512]  live until skip1 gemm_add
  u16* u1  = (u16*)(R + 0    * CH);   // [768]  written after h1 dead
  u16* au  = (u16*)(R + 1024 * CH);   // [768]
  u16* h2  = (u16*)(R + 0    * CH);   // [1024] u2raw/h2 (overwrites dead u1)

  auto cdiv = [](int a, int b){ return (a + b - 1) / b; };

  // graph preprocessing
  k_zero<<<cdiv(NN,256),256,0,stream>>>(deg, NN);
  k_zero<<<cdiv(NN,256),256,0,stream>>>(cur, NN);
  k_deg <<<cdiv(NE,256),256,0,stream>>>(ei, deg);
  k_dinv<<<cdiv(NN,256),256,0,stream>>>(deg, dinv);
  k_scan<<<1,1024,0,stream>>>(deg, offs);
  k_fill<<<cdiv(NE,256),256,0,stream>>>(ei, offs, cur, srcs);
  k_bounds<<<cdiv(NN,256),256,0,stream>>>(bat, startg);
  k_cast<<<cdiv(NN*32,256),256,0,stream>>>((const float4*)x, (ushort4*)xb, NN*32);

  auto agg = [&](const u16* in, u16* o, int C){
    int C8 = C / 8;
    int gb = cdiv(NN * C8, 256);
    switch (C8){
      case 16: k_agg_b<16><<<gb,256,0,stream>>>((const uint4*)in,(uint4*)o,dinv,offs,srcs); break;
      case 32: k_agg_b<32><<<gb,256,0,stream>>>((const uint4*)in,(uint4*)o,dinv,offs,srcs); break;
      case 48: k_agg_b<48><<<gb,256,0,stream>>>((const uint4*)in,(uint4*)o,dinv,offs,srcs); break;
      case 64: k_agg_b<64><<<gb,256,0,stream>>>((const uint4*)in,(uint4*)o,dinv,offs,srcs); break;
      case 96: k_agg_b<96><<<gb,256,0,stream>>>((const uint4*)in,(uint4*)o,dinv,offs,srcs); break;
      default: break;
    }
  };
  auto gemm_b = [&](const u16* A, const float* Bm, const float* bi, u16* Cc,
                    int K, int Nc, int mode){
    dim3 g(cdiv(NN,64), Nc/64);
    if (mode == 0)      k_gemm_b<0><<<g,256,0,stream>>>(A, Bm, bi, Cc, NN, K, Nc);
    else if (mode == 1) k_gemm_b<1><<<g,256,0,stream>>>(A, Bm, bi, Cc, NN, K, Nc);
    else                k_gemm_b<2><<<g,256,0,stream>>>(A, Bm, bi, Cc, NN, K, Nc);
  };
  auto bn = [&](u16* raw, const float* g, const float* be, int C){
    k_zero<<<cdiv(2048,256),256,0,stream>>>((int*)sacc, 2048);
    dim3 gs(cdiv(C,256), 64);
    k_bnstats_b<<<gs,256,0,stream>>>(raw, sacc, s2acc, C);
    k_bnfin<<<cdiv(C,256),256,0,stream>>>(sacc, s2acc, g, be, scv, shv, C);
    int total = NN * (C / 4);
    k_bnapply_b<<<cdiv(total,256),256,0,stream>>>((const ushort4*)raw, scv, shv,
                                                  (ushort4*)raw, C/4, total);
  };

  // stem: h0 = relu( agg(x) @ w0 + b0 )
  agg(xb, ax, 128);
  gemm_b(ax, w0, b0, h0, 128, 256, 1);
  // block0 (cin=256, mid=384, cout=512)
  agg(h0, ah0, 256);
  gemm_b(ah0, a_w1, a_b1, t1, 256, 384, 0);      // t1raw
  bn(t1, a_g1, a_be1, 384);                      // t1 = relu(bn(t1raw)) in place
  agg(t1, at, 384);
  gemm_b(at, a_w2, a_b2, h1, 384, 512, 0);       // t2raw
  bn(h1, a_g2, a_be2, 512);                      // relu(bn(t2raw)) in place
  gemm_b(ah0, a_w3, a_b3, h1, 256, 512, 2);      // h1 += ah0 @ w3 + b3
  // block1 (cin=512, mid=768, cout=1024)
  agg(h1, ah1, 512);
  gemm_b(ah1, c_w1, c_b1, u1, 512, 768, 0);      // u1raw (h1 dead now)
  bn(u1, c_g1, c_be1, 768);
  agg(u1, au, 768);
  gemm_b(au, c_w2, c_b2, h2, 768, 1024, 0);      // u2raw (u1 dead now)
  bn(h2, c_g2, c_be2, 1024);                     // relu(bn(u2raw)) in place
  gemm_b(ah1, c_w3, c_b3, h2, 512, 1024, 2);     // h2 += ah1 @ c_w3 + c_b3
  // pool + MLP (fp32)
  k_pool_b<<<NG,256,0,stream>>>(h2, startg, P);
  {
    dim3 g1(cdiv(NG,64), 1024/64);
    k_gemm<true><<<g1,256,0,stream>>>(P, mw1, mb1, Hh, NG, 1024, 1024);
    dim3 g2(cdiv(NG,64), 768/64);
    k_gemm<false><<<g2,256,0,stream>>>(Hh, mw2, mb2, out, NG, 1024, 768);
  }
}

// Round 3
// 1227.200 us; speedup vs baseline: 1.6753x; 1.6753x over previous
//
#include <hip/hip_runtime.h>
#include <cstdint>
#include <cstddef>

#define NN 20000
#define NE 320000
#define NG 256

typedef unsigned short u16;
typedef __attribute__((ext_vector_type(8))) short bf16x8;
typedef __attribute__((ext_vector_type(4))) float f32x4;

// ---------------- bf16 helpers (storage bf16, math fp32) ----------------
__device__ inline float b2f(u16 h){
  union { unsigned u; float f; } v; v.u = ((unsigned)h) << 16; return v.f;
}
__device__ inline u16 f2b(float f){
  union { float f; unsigned u; } v; v.f = f;
  unsigned r = v.u + 0x7FFFu + ((v.u >> 16) & 1u);   // round-nearest-even
  return (u16)(r >> 16);
}
__device__ inline void up2(unsigned u, float& a, float& b){
  union { unsigned u; float f; } x, y;
  x.u = u << 16; y.u = u & 0xffff0000u;
  a = x.f; b = y.f;
}
__device__ inline unsigned pk2(float a, float b){
  return (unsigned)f2b(a) | (((unsigned)f2b(b)) << 16);
}

__device__ inline void gload_lds16(const void* g, void* l){
  __builtin_amdgcn_global_load_lds(
      (const __attribute__((address_space(1))) unsigned int*)g,
      (__attribute__((address_space(3))) unsigned int*)l, 16, 0, 0);
}

// ---------------- utility kernels ----------------

__global__ void k_zero(int* __restrict__ p, int n){
  int i = blockIdx.x*blockDim.x + threadIdx.x;
  if (i < n) p[i] = 0;
}

__global__ void k_deg(const int* __restrict__ ei, int* __restrict__ deg){
  int e = blockIdx.x*blockDim.x + threadIdx.x;
  if (e < NE) atomicAdd(&deg[ei[NE + e]], 1);   // dst = ei[1][e]
}

__global__ void k_dinv(const int* __restrict__ deg, float* __restrict__ dinv){
  int i = blockIdx.x*blockDim.x + threadIdx.x;
  if (i < NN) dinv[i] = rsqrtf(1.0f + (float)deg[i]);
}

__global__ void k_scan(const int* __restrict__ counts, int* __restrict__ offs){
  __shared__ int sm[1024];
  int tid = threadIdx.x;
  int carry = 0;
  for (int base = 0; base < NN; base += 1024){
    int idx = base + tid;
    int v = (idx < NN) ? counts[idx] : 0;
    sm[tid] = v;
    __syncthreads();
    for (int d = 1; d < 1024; d <<= 1){
      int t = (tid >= d) ? sm[tid - d] : 0;
      __syncthreads();
      sm[tid] += t;
      __syncthreads();
    }
    int incl = sm[tid];
    if (idx < NN) offs[idx] = carry + incl - v;
    int total = sm[1023];
    __syncthreads();
    carry += total;
  }
  if (tid == 0) offs[NN] = carry;
}

__global__ void k_fill(const int* __restrict__ ei, const int* __restrict__ offs,
                       int* __restrict__ cur, int* __restrict__ srcs){
  int e = blockIdx.x*blockDim.x + threadIdx.x;
  if (e < NE){
    int s = ei[e];
    int d = ei[NE + e];
    int p = atomicAdd(&cur[d], 1);
    srcs[offs[d] + p] = s;
  }
}

__global__ void k_bounds(const int* __restrict__ batch, int* __restrict__ start){
  int i = blockIdx.x*blockDim.x + threadIdx.x;
  if (i < NN){
    int b  = batch[i];
    int bp = (i == 0) ? -1 : batch[i-1];
    for (int g = bp + 1; g <= b; g++) start[g] = i;
    if (i == NN - 1){
      for (int g = b + 1; g <= NG; g++) start[g] = NN;
    }
  }
}

__global__ void k_cast(const float4* __restrict__ x, ushort4* __restrict__ xb, int total4){
  int t = blockIdx.x*blockDim.x + threadIdx.x;
  if (t >= total4) return;
  float4 v = x[t];
  ushort4 o; o.x = f2b(v.x); o.y = f2b(v.y); o.z = f2b(v.z); o.w = f2b(v.w);
  xb[t] = o;
}

// weight prep: fp32 [K,N] row-major -> bf16 [N,K] row-major (tiled transpose)
__global__ __launch_bounds__(256) void k_wprep(const float* __restrict__ w,
                                               u16* __restrict__ wt, int K, int N){
  __shared__ float sm[64][65];
  int kb = blockIdx.x * 64, nb = blockIdx.y * 64;
  int tid = threadIdx.x;
  #pragma unroll
  for (int i = 0; i < 16; i++){
    int t = i*256 + tid;
    int r = t >> 6, c = t & 63;           // r = k-local, c = n-local
    sm[r][c] = w[(size_t)(kb + r) * N + nb + c];
  }
  __syncthreads();
  #pragma unroll
  for (int i = 0; i < 16; i++){
    int t = i*256 + tid;
    int r = t >> 6, c = t & 63;           // r = n-local, c = k-local
    wt[(size_t)(nb + r) * K + kb + c] = f2b(sm[c][r]);
  }
}

// ---------------- aggregation (bf16 in/out, fp32 accumulate) ----------------
template<int C8>
__global__ void k_agg_b(const uint4* __restrict__ in, uint4* __restrict__ out,
                        const float* __restrict__ dinv, const int* __restrict__ offs,
                        const int* __restrict__ srcs){
  int t = blockIdx.x*blockDim.x + threadIdx.x;
  if (t >= NN * C8) return;
  int i = t / C8;
  int c = t - i * C8;
  float di = dinv[i];
  float a[8], acc[8];
  uint4 xv = in[t];
  up2(xv.x, a[0], a[1]); up2(xv.y, a[2], a[3]);
  up2(xv.z, a[4], a[5]); up2(xv.w, a[6], a[7]);
  #pragma unroll
  for (int k = 0; k < 8; k++) acc[k] = a[k] * di;
  int e1 = offs[i + 1];
  for (int e = offs[i]; e < e1; e++){
    int s = srcs[e];
    float ds = dinv[s];
    uint4 yv = in[(size_t)s * C8 + c];
    up2(yv.x, a[0], a[1]); up2(yv.y, a[2], a[3]);
    up2(yv.z, a[4], a[5]); up2(yv.w, a[6], a[7]);
    #pragma unroll
    for (int k = 0; k < 8; k++) acc[k] = fmaf(a[k], ds, acc[k]);
  }
  #pragma unroll
  for (int k = 0; k < 8; k++) acc[k] *= di;
  uint4 o;
  o.x = pk2(acc[0], acc[1]); o.y = pk2(acc[2], acc[3]);
  o.z = pk2(acc[4], acc[5]); o.w = pk2(acc[6], acc[7]);
  out[t] = o;
}

// ---------------- MFMA GEMM: A bf16 [M,K], BT bf16 [N,K], C bf16 [M,N] ----------------
// 128x128 tile, BK=64, 256 threads (4 waves, 2x2), 4x4 16x16x32 frags/wave.
// LDS XOR-swizzle: slot (row, col8) holds global (row, col8 ^ (row&7)).
// MODE: 0=bias, 1=bias+relu, 2=bias+add-into-C
template<int MODE>
__global__ __launch_bounds__(256, 2) void k_mfma(const u16* __restrict__ A,
                                                 const u16* __restrict__ BT,
                                                 const float* __restrict__ bias,
                                                 u16* __restrict__ C,
                                                 int M, int K, int Nc){
  __shared__ u16 As[128*64];
  __shared__ u16 Bs[128*64];
  const int tid = threadIdx.x;
  const int lane = tid & 63;
  const int quad = lane >> 4;
  const int l16 = lane & 15;
  const int wid = tid >> 6;
  const int wm = wid & 1, wn = wid >> 1;
  const int bm = blockIdx.x * 128, bn = blockIdx.y * 128;

  f32x4 acc[4][4];
  #pragma unroll
  for (int i = 0; i < 4; i++)
    #pragma unroll
    for (int j = 0; j < 4; j++)
      acc[i][j] = (f32x4){0.f, 0.f, 0.f, 0.f};

  const int srow = tid >> 3;     // staging row base (+32*i)
  const int scol8 = tid & 7;     // staging col8 slot
  for (int k0 = 0; k0 < K; k0 += 64){
    #pragma unroll
    for (int i = 0; i < 4; i++){
      int row = i*32 + srow;
      int gc = (scol8 ^ (row & 7)) * 8;
      int lofs = row*64 + scol8*8;
      gload_lds16(A + (size_t)(bm + row) * K + k0 + gc, As + lofs);
      gload_lds16(BT + (size_t)(bn + row) * K + k0 + gc, Bs + lofs);
    }
    __syncthreads();
    #pragma unroll
    for (int kk = 0; kk < 2; kk++){
      const int col8 = kk*4 + quad;
      bf16x8 af[4], bfr[4];
      #pragma unroll
      for (int mi = 0; mi < 4; mi++){
        int row = wm*64 + mi*16 + l16;
        af[mi] = *(const bf16x8*)(As + row*64 + ((col8 ^ (row & 7)) * 8));
      }
      #pragma unroll
      for (int ni = 0; ni < 4; ni++){
        int row = wn*64 + ni*16 + l16;
        bfr[ni] = *(const bf16x8*)(Bs + row*64 + ((col8 ^ (row & 7)) * 8));
      }
      #pragma unroll
      for (int mi = 0; mi < 4; mi++)
        #pragma unroll
        for (int ni = 0; ni < 4; ni++)
          acc[mi][ni] = __builtin_amdgcn_mfma_f32_16x16x32_bf16(af[mi], bfr[ni], acc[mi][ni], 0, 0, 0);
    }
    __syncthreads();
  }
  // epilogue: C/D layout col=lane&15, row=quad*4+reg
  #pragma unroll
  for (int ni = 0; ni < 4; ni++){
    int col = bn + wn*64 + ni*16 + l16;
    float bb = bias[col];
    #pragma unroll
    for (int mi = 0; mi < 4; mi++){
      int rbase = bm + wm*64 + mi*16 + quad*4;
      #pragma unroll
      for (int r = 0; r < 4; r++){
        int row = rbase + r;
        if (row < M){
          float v = acc[mi][ni][r] + bb;
          if (MODE == 1) v = fmaxf(v, 0.f);
          u16* cp = C + (size_t)row * Nc + col;
          if (MODE == 2) v += b2f(*cp);
          *cp = f2b(v);
        }
      }
    }
  }
}

// ---------------- fp32 GEMM (MLP tail, small M) ----------------
template<bool RELU>
__global__ __launch_bounds__(256) void k_gemm(const float* __restrict__ A,
                                              const float* __restrict__ B,
                                              const float* __restrict__ bias,
                                              float* __restrict__ C,
                                              int M, int K, int Nc){
  __shared__ float As[16][68];
  __shared__ float Bs[16][64];
  const int tid = threadIdx.x;
  const int tx = tid & 15, ty = tid >> 4;
  const int bm = blockIdx.x * 64, bn = blockIdx.y * 64;
  const int arow = tid >> 2, akq = (tid & 3) << 2;
  const int brow = tid >> 4, bcol = (tid & 15) << 2;
  float acc[4][4] = {{0.f}};
  const bool aval = (bm + arow) < M;
  const float* Aptr = A + (size_t)(bm + arow) * K + akq;
  const float* Bptr = B + (size_t)brow * Nc + bn + bcol;
  for (int k0 = 0; k0 < K; k0 += 16){
    float4 av = make_float4(0.f, 0.f, 0.f, 0.f);
    if (aval) av = *(const float4*)(Aptr + k0);
    float4 bv = *(const float4*)(Bptr + (size_t)k0 * Nc);
    As[akq + 0][arow] = av.x;
    As[akq + 1][arow] = av.y;
    As[akq + 2][arow] = av.z;
    As[akq + 3][arow] = av.w;
    *(float4*)&Bs[brow][bcol] = bv;
    __syncthreads();
    #pragma unroll
    for (int kk = 0; kk < 16; kk++){
      const float4 a = *(const float4*)(&As[kk][ty << 2]);
      const float4 b = *(const float4*)(&Bs[kk][tx << 2]);
      const float ar[4] = {a.x, a.y, a.z, a.w};
      const float br[4] = {b.x, b.y, b.z, b.w};
      #pragma unroll
      for (int i = 0; i < 4; i++)
        #pragma unroll
        for (int j = 0; j < 4; j++)
          acc[i][j] = fmaf(ar[i], br[j], acc[i][j]);
    }
    __syncthreads();
  }
  const int col = bn + (tx << 2);
  const float4 bb = *(const float4*)(bias + col);
  #pragma unroll
  for (int i = 0; i < 4; i++){
    int row = bm + (ty << 2) + i;
    if (row < M){
      float4 o;
      o.x = acc[i][0] + bb.x;
      o.y = acc[i][1] + bb.y;
      o.z = acc[i][2] + bb.z;
      o.w = acc[i][3] + bb.w;
      if (RELU){
        o.x = fmaxf(o.x, 0.f); o.y = fmaxf(o.y, 0.f);
        o.z = fmaxf(o.z, 0.f); o.w = fmaxf(o.w, 0.f);
      }
      *(float4*)(C + (size_t)row * Nc + col) = o;
    }
  }
}

// ---------------- BatchNorm (bf16 raw, fp32 stats) ----------------

__global__ void k_bnstats_b(const u16* __restrict__ h, float* __restrict__ sacc,
                            float* __restrict__ s2acc, int C){
  int c = blockIdx.x * blockDim.x + threadIdx.x;
  if (c >= C) return;
  int sl = blockIdx.y, nsl = gridDim.y;
  int r0 = (int)(((long long)NN * sl) / nsl);
  int r1 = (int)(((long long)NN * (sl + 1)) / nsl);
  float s = 0.f, s2 = 0.f;
  for (int r = r0; r < r1; r++){
    float v = b2f(h[(size_t)r * C + c]);
    s += v; s2 += v * v;
  }
  atomicAdd(&sacc[c], s);
  atomicAdd(&s2acc[c], s2);
}

__global__ void k_bnfin(const float* __restrict__ sacc, const float* __restrict__ s2acc,
                        const float* __restrict__ g, const float* __restrict__ be,
                        float* __restrict__ scale, float* __restrict__ shift, int C){
  int c = blockIdx.x * blockDim.x + threadIdx.x;
  if (c >= C) return;
  float m = sacc[c] * (1.0f / NN);
  float v = s2acc[c] * (1.0f / NN) - m * m;
  float rs = rsqrtf(v + 1e-5f);
  float sc = g[c] * rs;
  scale[c] = sc;
  shift[c] = be[c] - m * sc;
}

__global__ void k_bnapply_b(const ushort4* __restrict__ raw, const float* __restrict__ scale,
                            const float* __restrict__ shift, ushort4* __restrict__ out,
                            int C4, int total){
  int t = blockIdx.x * blockDim.x + threadIdx.x;
  if (t >= total) return;
  int c4 = t % C4;
  ushort4 v = raw[t];
  float4 sc = ((const float4*)scale)[c4];
  float4 sh = ((const float4*)shift)[c4];
  float r0 = fmaxf(fmaf(b2f(v.x), sc.x, sh.x), 0.f);
  float r1 = fmaxf(fmaf(b2f(v.y), sc.y, sh.y), 0.f);
  float r2 = fmaxf(fmaf(b2f(v.z), sc.z, sh.z), 0.f);
  float r3 = fmaxf(fmaf(b2f(v.w), sc.w, sh.w), 0.f);
  ushort4 o; o.x = f2b(r0); o.y = f2b(r1); o.z = f2b(r2); o.w = f2b(r3);
  out[t] = o;
}

// ---------------- mean pool: h2 bf16 [NN,1024] -> pooled fp32 [NG,1024] ----------------
__global__ void k_pool_b(const u16* __restrict__ h, const int* __restrict__ start,
                         float* __restrict__ pooled){
  int g = blockIdx.x;
  int c = threadIdx.x << 2;
  int r0 = start[g], r1 = start[g + 1];
  float a0 = 0.f, a1 = 0.f, a2 = 0.f, a3 = 0.f;
  for (int r = r0; r < r1; r++){
    ushort4 v = *(const ushort4*)(h + (size_t)r * 1024 + c);
    a0 += b2f(v.x); a1 += b2f(v.y); a2 += b2f(v.z); a3 += b2f(v.w);
  }
  float inv = (r1 > r0) ? (1.0f / (float)(r1 - r0)) : 0.0f;
  float4 o; o.x = a0 * inv; o.y = a1 * inv; o.z = a2 * inv; o.w = a3 * inv;
  *(float4*)(pooled + (size_t)g * 1024 + c) = o;
}

// ---------------- host launcher ----------------

extern "C" void kernel_launch(void* const* d_in, const int* in_sizes, int n_in,
                              void* d_out, int out_size, void* d_ws, size_t ws_size,
                              hipStream_t stream) {
  const float* x    = (const float*)d_in[0];
  const int*   ei   = (const int*)d_in[1];
  const int*   bat  = (const int*)d_in[2];
  const float* w0   = (const float*)d_in[3];
  const float* b0   = (const float*)d_in[4];
  const float* a_w1 = (const float*)d_in[5],  *a_b1  = (const float*)d_in[6];
  const float* a_g1 = (const float*)d_in[7],  *a_be1 = (const float*)d_in[8];
  const float* a_w2 = (const float*)d_in[9],  *a_b2  = (const float*)d_in[10];
  const float* a_g2 = (const float*)d_in[11], *a_be2 = (const float*)d_in[12];
  const float* a_w3 = (const float*)d_in[13], *a_b3  = (const float*)d_in[14];
  const float* c_w1 = (const float*)d_in[15], *c_b1  = (const float*)d_in[16];
  const float* c_g1 = (const float*)d_in[17], *c_be1 = (const float*)d_in[18];
  const float* c_w2 = (const float*)d_in[19], *c_b2  = (const float*)d_in[20];
  const float* c_g2 = (const float*)d_in[21], *c_be2 = (const float*)d_in[22];
  const float* c_w3 = (const float*)d_in[23], *c_b3  = (const float*)d_in[24];
  const float* mw1  = (const float*)d_in[25], *mb1   = (const float*)d_in[26];
  const float* mw2  = (const float*)d_in[27], *mb2   = (const float*)d_in[28];
  float* out = (float*)d_out;

  char* pp = (char*)d_ws;
  auto alloc = [&](size_t b)->char*{ char* r = pp; pp += (b + 255) & ~(size_t)255; return r; };

  // activation region: 2304 channel-slots (peak antichain {ah1,au,u2raw} = 512+768+1024)
  const size_t CH = (size_t)NN * 2;
  char* R = alloc(2304 * CH);                      // 92.16 MB
  float* dinv = (float*)alloc((size_t)NN * 4);
  int* deg    = (int*)alloc((size_t)NN * 4);
  int* offs   = (int*)alloc((size_t)(NN + 1) * 4);
  int* cur    = (int*)alloc((size_t)NN * 4);
  int* srcs   = (int*)alloc((size_t)NE * 4);
  int* startg = (int*)alloc((size_t)(NG + 1) * 4);
  float* sacc = (float*)alloc(2048 * 4);
  float* s2acc = sacc + 1024;
  float* scv  = (float*)alloc(1024 * 4);
  float* shv  = (float*)alloc(1024 * 4);
  // bf16-transposed weights; overlaid with MLP P/Hh (disjoint lifetimes)
  u16* WT  = (u16*)alloc(2162688 * 2);             // 4.33 MB
  u16* wt0  = WT;                // 256x128
  u16* wtA1 = WT + 32768;        // 384x256
  u16* wtA2 = WT + 131072;       // 512x384
  u16* wtA3 = WT + 327680;       // 512x256
  u16* wtC1 = WT + 458752;       // 768x512
  u16* wtC2 = WT + 851968;       // 1024x768
  u16* wtC3 = WT + 1638400;      // 1024x512
  float* P  = (float*)WT;                          // [256,1024] fp32, live after last graph gemm
  float* Hh = P + (size_t)NG * 1024;

  // liveness-scheduled slots (channel index into R)
  auto slot = [&](int s)->u16*{ return (u16*)(R + (size_t)s * CH); };
  u16* xb  = slot(512);    // [512,640)   p0-p1
  u16* ax  = slot(0);      // [0,128)     p1-p2
  u16* h0  = slot(128);    // [128,384)   p2-p3
  u16* ah0 = slot(1664);   // [1664,1920) p3-p7b
  u16* t1  = slot(1920);   // [1920,2304) p4-p6
  u16* at  = slot(1280);   // [1280,1664) p6-p7
  u16* h1  = slot(768);    // [768,1280)  p7-p8
  u16* ah1 = slot(1792);   // [1792,2304) p8-p12
  u16* u1  = slot(0);      // [0,768)     p9-p10
  u16* au  = slot(1024);   // [1024,1792) p10-p11
  u16* h2  = slot(0);      // [0,1024)    p11-pool

  auto cdiv = [](int a, int b){ return (a + b - 1) / b; };

  // graph preprocessing
  k_zero<<<cdiv(NN,256),256,0,stream>>>(deg, NN);
  k_zero<<<cdiv(NN,256),256,0,stream>>>(cur, NN);
  k_deg <<<cdiv(NE,256),256,0,stream>>>(ei, deg);
  k_dinv<<<cdiv(NN,256),256,0,stream>>>(deg, dinv);
  k_scan<<<1,1024,0,stream>>>(deg, offs);
  k_fill<<<cdiv(NE,256),256,0,stream>>>(ei, offs, cur, srcs);
  k_bounds<<<cdiv(NN,256),256,0,stream>>>(bat, startg);
  k_cast<<<cdiv(NN*32,256),256,0,stream>>>((const float4*)x, (ushort4*)xb, NN*32);

  // weight prep (fp32 [K,N] -> bf16 [N,K])
  k_wprep<<<dim3(2,4),  256,0,stream>>>(w0,   wt0,  128, 256);
  k_wprep<<<dim3(4,6),  256,0,stream>>>(a_w1, wtA1, 256, 384);
  k_wprep<<<dim3(6,8),  256,0,stream>>>(a_w2, wtA2, 384, 512);
  k_wprep<<<dim3(4,8),  256,0,stream>>>(a_w3, wtA3, 256, 512);
  k_wprep<<<dim3(8,12), 256,0,stream>>>(c_w1, wtC1, 512, 768);
  k_wprep<<<dim3(12,16),256,0,stream>>>(c_w2, wtC2, 768, 1024);
  k_wprep<<<dim3(8,16), 256,0,stream>>>(c_w3, wtC3, 512, 1024);

  auto agg = [&](const u16* in, u16* o, int C){
    int C8 = C / 8;
    int gb = cdiv(NN * C8, 256);
    switch (C8){
      case 16: k_agg_b<16><<<gb,256,0,stream>>>((const uint4*)in,(uint4*)o,dinv,offs,srcs); break;
      case 32: k_agg_b<32><<<gb,256,0,stream>>>((const uint4*)in,(uint4*)o,dinv,offs,srcs); break;
      case 48: k_agg_b<48><<<gb,256,0,stream>>>((const uint4*)in,(uint4*)o,dinv,offs,srcs); break;
      case 64: k_agg_b<64><<<gb,256,0,stream>>>((const uint4*)in,(uint4*)o,dinv,offs,srcs); break;
      case 96: k_agg_b<96><<<gb,256,0,stream>>>((const uint4*)in,(uint4*)o,dinv,offs,srcs); break;
      default: break;
    }
  };
  auto gemm_m = [&](const u16* A, const u16* BT_, const float* bi, u16* Cc,
                    int K, int Nc, int mode){
    dim3 g(cdiv(NN,128), Nc/128);
    if (mode == 0)      k_mfma<0><<<g,256,0,stream>>>(A, BT_, bi, Cc, NN, K, Nc);
    else if (mode == 1) k_mfma<1><<<g,256,0,stream>>>(A, BT_, bi, Cc, NN, K, Nc);
    else                k_mfma<2><<<g,256,0,stream>>>(A, BT_, bi, Cc, NN, K, Nc);
  };
  auto bn = [&](u16* raw, const float* g, const float* be, int C){
    k_zero<<<cdiv(2048,256),256,0,stream>>>((int*)sacc, 2048);
    dim3 gs(cdiv(C,256), 64);
    k_bnstats_b<<<gs,256,0,stream>>>(raw, sacc, s2acc, C);
    k_bnfin<<<cdiv(C,256),256,0,stream>>>(sacc, s2acc, g, be, scv, shv, C);
    int total = NN * (C / 4);
    k_bnapply_b<<<cdiv(total,256),256,0,stream>>>((const ushort4*)raw, scv, shv,
                                                  (ushort4*)raw, C/4, total);
  };

  // stem
  agg(xb, ax, 128);                         // p1
  gemm_m(ax, wt0, b0, h0, 128, 256, 1);     // p2
  // block0 (256 -> 384 -> 512)
  agg(h0, ah0, 256);                        // p3
  gemm_m(ah0, wtA1, a_b1, t1, 256, 384, 0); // p4
  bn(t1, a_g1, a_be1, 384);                 // p5
  agg(t1, at, 384);                         // p6
  gemm_m(at, wtA2, a_b2, h1, 384, 512, 0);  // p7
  bn(h1, a_g2, a_be2, 512);                 // p7a
  gemm_m(ah0, wtA3, a_b3, h1, 256, 512, 2); // p7b: h1 += ah0@w3+b3
  // block1 (512 -> 768 -> 1024)
  agg(h1, ah1, 512);                        // p8
  gemm_m(ah1, wtC1, c_b1, u1, 512, 768, 0); // p9
  bn(u1, c_g1, c_be1, 768);                 // p9a
  agg(u1, au, 768);                         // p10
  gemm_m(au, wtC2, c_b2, h2, 768, 1024, 0); // p11
  bn(h2, c_g2, c_be2, 1024);                // p11a
  gemm_m(ah1, wtC3, c_b3, h2, 512, 1024, 2);// p12: h2 += ah1@c_w3+c_b3
  // pool + MLP (fp32)
  k_pool_b<<<NG,256,0,stream>>>(h2, startg, P);
  {
    dim3 g1(cdiv(NG,64), 1024/64);
    k_gemm<true><<<g1,256,0,stream>>>(P, mw1, mb1, Hh, NG, 1024, 1024);
    dim3 g2(cdiv(NG,64), 768/64);
    k_gemm<false><<<g2,256,0,stream>>>(Hh, mw2, mb2, out, NG, 1024, 768);
  }
}

// Round 4
// 916.112 us; speedup vs baseline: 2.2442x; 1.3396x over previous
//
#include <hip/hip_runtime.h>
#include <cstdint>
#include <cstddef>

#define NN 20000
#define NE 320000
#define NG 256

typedef unsigned short u16;
typedef __attribute__((ext_vector_type(8))) short bf16x8;
typedef __attribute__((ext_vector_type(4))) float f32x4;

// ---------------- bf16 helpers (storage bf16, math fp32) ----------------
__device__ inline float b2f(u16 h){
  union { unsigned u; float f; } v; v.u = ((unsigned)h) << 16; return v.f;
}
__device__ inline u16 f2b(float f){
  union { float f; unsigned u; } v; v.f = f;
  unsigned r = v.u + 0x7FFFu + ((v.u >> 16) & 1u);   // round-nearest-even
  return (u16)(r >> 16);
}
__device__ inline void up2(unsigned u, float& a, float& b){
  union { unsigned u; float f; } x, y;
  x.u = u << 16; y.u = u & 0xffff0000u;
  a = x.f; b = y.f;
}
__device__ inline unsigned pk2(float a, float b){
  return (unsigned)f2b(a) | (((unsigned)f2b(b)) << 16);
}

__device__ inline void gload_lds16(const void* g, void* l){
  __builtin_amdgcn_global_load_lds(
      (const __attribute__((address_space(1))) unsigned int*)g,
      (__attribute__((address_space(3))) unsigned int*)l, 16, 0, 0);
}

// ---------------- utility kernels ----------------

__global__ void k_zero(int* __restrict__ p, int n){
  int i = blockIdx.x*blockDim.x + threadIdx.x;
  if (i < n) p[i] = 0;
}

__global__ void k_deg(const int* __restrict__ ei, int* __restrict__ deg){
  int e = blockIdx.x*blockDim.x + threadIdx.x;
  if (e < NE) atomicAdd(&deg[ei[NE + e]], 1);   // dst = ei[1][e]
}

__global__ void k_dinv(const int* __restrict__ deg, float* __restrict__ dinv){
  int i = blockIdx.x*blockDim.x + threadIdx.x;
  if (i < NN) dinv[i] = rsqrtf(1.0f + (float)deg[i]);
}

__global__ void k_scan(const int* __restrict__ counts, int* __restrict__ offs){
  __shared__ int sm[1024];
  int tid = threadIdx.x;
  int carry = 0;
  for (int base = 0; base < NN; base += 1024){
    int idx = base + tid;
    int v = (idx < NN) ? counts[idx] : 0;
    sm[tid] = v;
    __syncthreads();
    for (int d = 1; d < 1024; d <<= 1){
      int t = (tid >= d) ? sm[tid - d] : 0;
      __syncthreads();
      sm[tid] += t;
      __syncthreads();
    }
    int incl = sm[tid];
    if (idx < NN) offs[idx] = carry + incl - v;
    int total = sm[1023];
    __syncthreads();
    carry += total;
  }
  if (tid == 0) offs[NN] = carry;
}

__global__ void k_fill(const int* __restrict__ ei, const int* __restrict__ offs,
                       int* __restrict__ cur, int* __restrict__ srcs){
  int e = blockIdx.x*blockDim.x + threadIdx.x;
  if (e < NE){
    int s = ei[e];
    int d = ei[NE + e];
    int p = atomicAdd(&cur[d], 1);
    srcs[offs[d] + p] = s;
  }
}

__global__ void k_bounds(const int* __restrict__ batch, int* __restrict__ start){
  int i = blockIdx.x*blockDim.x + threadIdx.x;
  if (i < NN){
    int b  = batch[i];
    int bp = (i == 0) ? -1 : batch[i-1];
    for (int g = bp + 1; g <= b; g++) start[g] = i;
    if (i == NN - 1){
      for (int g = b + 1; g <= NG; g++) start[g] = NN;
    }
  }
}

__global__ void k_cast(const float4* __restrict__ x, ushort4* __restrict__ xb, int total4){
  int t = blockIdx.x*blockDim.x + threadIdx.x;
  if (t >= total4) return;
  float4 v = x[t];
  ushort4 o; o.x = f2b(v.x); o.y = f2b(v.y); o.z = f2b(v.z); o.w = f2b(v.w);
  xb[t] = o;
}

// weight prep: fp32 [K,N] row-major -> bf16 [N,K] row-major (tiled transpose)
__global__ __launch_bounds__(256) void k_wprep(const float* __restrict__ w,
                                               u16* __restrict__ wt, int K, int N){
  __shared__ float sm[64][65];
  int kb = blockIdx.x * 64, nb = blockIdx.y * 64;
  int tid = threadIdx.x;
  #pragma unroll
  for (int i = 0; i < 16; i++){
    int t = i*256 + tid;
    int r = t >> 6, c = t & 63;
    sm[r][c] = w[(size_t)(kb + r) * N + nb + c];
  }
  __syncthreads();
  #pragma unroll
  for (int i = 0; i < 16; i++){
    int t = i*256 + tid;
    int r = t >> 6, c = t & 63;
    wt[(size_t)(nb + r) * K + kb + c] = f2b(sm[c][r]);
  }
}

// ---------------- aggregation (bf16 in/out, fp32 accumulate) ----------------
template<int C8>
__global__ void k_agg_b(const uint4* __restrict__ in, uint4* __restrict__ out,
                        const float* __restrict__ dinv, const int* __restrict__ offs,
                        const int* __restrict__ srcs){
  int t = blockIdx.x*blockDim.x + threadIdx.x;
  if (t >= NN * C8) return;
  int i = t / C8;
  int c = t - i * C8;
  float di = dinv[i];
  float a[8], acc[8];
  uint4 xv = in[t];
  up2(xv.x, a[0], a[1]); up2(xv.y, a[2], a[3]);
  up2(xv.z, a[4], a[5]); up2(xv.w, a[6], a[7]);
  #pragma unroll
  for (int k = 0; k < 8; k++) acc[k] = a[k] * di;
  int e1 = offs[i + 1];
  for (int e = offs[i]; e < e1; e++){
    int s = srcs[e];
    float ds = dinv[s];
    uint4 yv = in[(size_t)s * C8 + c];
    up2(yv.x, a[0], a[1]); up2(yv.y, a[2], a[3]);
    up2(yv.z, a[4], a[5]); up2(yv.w, a[6], a[7]);
    #pragma unroll
    for (int k = 0; k < 8; k++) acc[k] = fmaf(a[k], ds, acc[k]);
  }
  #pragma unroll
  for (int k = 0; k < 8; k++) acc[k] *= di;
  uint4 o;
  o.x = pk2(acc[0], acc[1]); o.y = pk2(acc[2], acc[3]);
  o.z = pk2(acc[4], acc[5]); o.w = pk2(acc[6], acc[7]);
  out[t] = o;
}

// ---------------- MFMA GEMM: A bf16 [M,K], BT bf16 [N,K], C bf16 [M,N] ----------------
// 128x128 tile, BK=64, 256 threads (4 waves, 2x2), 4x4 16x16x32 frags/wave.
// LDS XOR-swizzle: slot (row, col8) holds global (row, col8 ^ (row&7)).
// MODE: 0=bias, 1=bias+relu, 2=bias+add-into-C
// STATS: accumulate per-column sum/sumsq of (acc+bias) into sacc/s2acc (BN fusion)
template<int MODE, bool STATS>
__global__ __launch_bounds__(256, 2) void k_mfma(const u16* __restrict__ A,
                                                 const u16* __restrict__ BT,
                                                 const float* __restrict__ bias,
                                                 u16* __restrict__ C,
                                                 float* __restrict__ sacc,
                                                 float* __restrict__ s2acc,
                                                 int M, int K, int Nc){
  __shared__ u16 As[128*64];
  __shared__ u16 Bs[128*64];
  const int tid = threadIdx.x;
  const int lane = tid & 63;
  const int quad = lane >> 4;
  const int l16 = lane & 15;
  const int wid = tid >> 6;
  const int wm = wid & 1, wn = wid >> 1;
  const int bm = blockIdx.x * 128, bn = blockIdx.y * 128;

  f32x4 acc[4][4];
  #pragma unroll
  for (int i = 0; i < 4; i++)
    #pragma unroll
    for (int j = 0; j < 4; j++)
      acc[i][j] = (f32x4){0.f, 0.f, 0.f, 0.f};

  const int srow = tid >> 3;
  const int scol8 = tid & 7;
  for (int k0 = 0; k0 < K; k0 += 64){
    #pragma unroll
    for (int i = 0; i < 4; i++){
      int row = i*32 + srow;
      int gc = (scol8 ^ (row & 7)) * 8;
      int lofs = row*64 + scol8*8;
      gload_lds16(A + (size_t)(bm + row) * K + k0 + gc, As + lofs);
      gload_lds16(BT + (size_t)(bn + row) * K + k0 + gc, Bs + lofs);
    }
    __syncthreads();
    #pragma unroll
    for (int kk = 0; kk < 2; kk++){
      const int col8 = kk*4 + quad;
      bf16x8 af[4], bfr[4];
      #pragma unroll
      for (int mi = 0; mi < 4; mi++){
        int row = wm*64 + mi*16 + l16;
        af[mi] = *(const bf16x8*)(As + row*64 + ((col8 ^ (row & 7)) * 8));
      }
      #pragma unroll
      for (int ni = 0; ni < 4; ni++){
        int row = wn*64 + ni*16 + l16;
        bfr[ni] = *(const bf16x8*)(Bs + row*64 + ((col8 ^ (row & 7)) * 8));
      }
      #pragma unroll
      for (int mi = 0; mi < 4; mi++)
        #pragma unroll
        for (int ni = 0; ni < 4; ni++)
          acc[mi][ni] = __builtin_amdgcn_mfma_f32_16x16x32_bf16(af[mi], bfr[ni], acc[mi][ni], 0, 0, 0);
    }
    __syncthreads();
  }
  // epilogue: C/D layout col=lane&15, row=quad*4+reg
  #pragma unroll
  for (int ni = 0; ni < 4; ni++){
    int col = bn + wn*64 + ni*16 + l16;
    float bb = bias[col];
    float s = 0.f, s2 = 0.f;
    #pragma unroll
    for (int mi = 0; mi < 4; mi++){
      int rbase = bm + wm*64 + mi*16 + quad*4;
      #pragma unroll
      for (int r = 0; r < 4; r++){
        int row = rbase + r;
        if (row < M){
          float v = acc[mi][ni][r] + bb;
          if (STATS){ s += v; s2 += v * v; }
          if (MODE == 1) v = fmaxf(v, 0.f);
          u16* cp = C + (size_t)row * Nc + col;
          if (MODE == 2) v += b2f(*cp);
          *cp = f2b(v);
        }
      }
    }
    if (STATS){
      // reduce across the 4 quads that share this column (lanes l16, l16+16, +32, +48)
      s  += __shfl_xor(s, 16, 64);  s  += __shfl_xor(s, 32, 64);
      s2 += __shfl_xor(s2, 16, 64); s2 += __shfl_xor(s2, 32, 64);
      if (quad == 0){
        atomicAdd(&sacc[col], s);
        atomicAdd(&s2acc[col], s2);
      }
    }
  }
}

// ---------------- fp32 GEMM (MLP tail, small M) ----------------
template<bool RELU>
__global__ __launch_bounds__(256) void k_gemm(const float* __restrict__ A,
                                              const float* __restrict__ B,
                                              const float* __restrict__ bias,
                                              float* __restrict__ C,
                                              int M, int K, int Nc){
  __shared__ float As[16][68];
  __shared__ float Bs[16][64];
  const int tid = threadIdx.x;
  const int tx = tid & 15, ty = tid >> 4;
  const int bm = blockIdx.x * 64, bn = blockIdx.y * 64;
  const int arow = tid >> 2, akq = (tid & 3) << 2;
  const int brow = tid >> 4, bcol = (tid & 15) << 2;
  float acc[4][4] = {{0.f}};
  const bool aval = (bm + arow) < M;
  const float* Aptr = A + (size_t)(bm + arow) * K + akq;
  const float* Bptr = B + (size_t)brow * Nc + bn + bcol;
  for (int k0 = 0; k0 < K; k0 += 16){
    float4 av = make_float4(0.f, 0.f, 0.f, 0.f);
    if (aval) av = *(const float4*)(Aptr + k0);
    float4 bv = *(const float4*)(Bptr + (size_t)k0 * Nc);
    As[akq + 0][arow] = av.x;
    As[akq + 1][arow] = av.y;
    As[akq + 2][arow] = av.z;
    As[akq + 3][arow] = av.w;
    *(float4*)&Bs[brow][bcol] = bv;
    __syncthreads();
    #pragma unroll
    for (int kk = 0; kk < 16; kk++){
      const float4 a = *(const float4*)(&As[kk][ty << 2]);
      const float4 b = *(const float4*)(&Bs[kk][tx << 2]);
      const float ar[4] = {a.x, a.y, a.z, a.w};
      const float br[4] = {b.x, b.y, b.z, b.w};
      #pragma unroll
      for (int i = 0; i < 4; i++)
        #pragma unroll
        for (int j = 0; j < 4; j++)
          acc[i][j] = fmaf(ar[i], br[j], acc[i][j]);
    }
    __syncthreads();
  }
  const int col = bn + (tx << 2);
  const float4 bb = *(const float4*)(bias + col);
  #pragma unroll
  for (int i = 0; i < 4; i++){
    int row = bm + (ty << 2) + i;
    if (row < M){
      float4 o;
      o.x = acc[i][0] + bb.x;
      o.y = acc[i][1] + bb.y;
      o.z = acc[i][2] + bb.z;
      o.w = acc[i][3] + bb.w;
      if (RELU){
        o.x = fmaxf(o.x, 0.f); o.y = fmaxf(o.y, 0.f);
        o.z = fmaxf(o.z, 0.f); o.w = fmaxf(o.w, 0.f);
      }
      *(float4*)(C + (size_t)row * Nc + col) = o;
    }
  }
}

// ---------------- BatchNorm finalize + apply ----------------

__global__ void k_bnfin(const float* __restrict__ sacc, const float* __restrict__ s2acc,
                        const float* __restrict__ g, const float* __restrict__ be,
                        float* __restrict__ scale, float* __restrict__ shift, int C){
  int c = blockIdx.x * blockDim.x + threadIdx.x;
  if (c >= C) return;
  float m = sacc[c] * (1.0f / NN);
  float v = s2acc[c] * (1.0f / NN) - m * m;
  float rs = rsqrtf(v + 1e-5f);
  float sc = g[c] * rs;
  scale[c] = sc;
  shift[c] = be[c] - m * sc;
}

__global__ void k_bnapply_b(const ushort4* __restrict__ raw, const float* __restrict__ scale,
                            const float* __restrict__ shift, ushort4* __restrict__ out,
                            int C4, int total){
  int t = blockIdx.x * blockDim.x + threadIdx.x;
  if (t >= total) return;
  int c4 = t % C4;
  ushort4 v = raw[t];
  float4 sc = ((const float4*)scale)[c4];
  float4 sh = ((const float4*)shift)[c4];
  float r0 = fmaxf(fmaf(b2f(v.x), sc.x, sh.x), 0.f);
  float r1 = fmaxf(fmaf(b2f(v.y), sc.y, sh.y), 0.f);
  float r2 = fmaxf(fmaf(b2f(v.z), sc.z, sh.z), 0.f);
  float r3 = fmaxf(fmaf(b2f(v.w), sc.w, sh.w), 0.f);
  ushort4 o; o.x = f2b(r0); o.y = f2b(r1); o.z = f2b(r2); o.w = f2b(r3);
  out[t] = o;
}

// ---------------- mean pool: h2 bf16 [NN,1024] -> pooled fp32 [NG,1024] ----------------
__global__ void k_pool_b(const u16* __restrict__ h, const int* __restrict__ start,
                         float* __restrict__ pooled){
  int g = blockIdx.x;
  int c = threadIdx.x << 2;
  int r0 = start[g], r1 = start[g + 1];
  float a0 = 0.f, a1 = 0.f, a2 = 0.f, a3 = 0.f;
  for (int r = r0; r < r1; r++){
    ushort4 v = *(const ushort4*)(h + (size_t)r * 1024 + c);
    a0 += b2f(v.x); a1 += b2f(v.y); a2 += b2f(v.z); a3 += b2f(v.w);
  }
  float inv = (r1 > r0) ? (1.0f / (float)(r1 - r0)) : 0.0f;
  float4 o; o.x = a0 * inv; o.y = a1 * inv; o.z = a2 * inv; o.w = a3 * inv;
  *(float4*)(pooled + (size_t)g * 1024 + c) = o;
}

// ---------------- host launcher ----------------

extern "C" void kernel_launch(void* const* d_in, const int* in_sizes, int n_in,
                              void* d_out, int out_size, void* d_ws, size_t ws_size,
                              hipStream_t stream) {
  const float* x    = (const float*)d_in[0];
  const int*   ei   = (const int*)d_in[1];
  const int*   bat  = (const int*)d_in[2];
  const float* w0   = (const float*)d_in[3];
  const float* b0   = (const float*)d_in[4];
  const float* a_w1 = (const float*)d_in[5],  *a_b1  = (const float*)d_in[6];
  const float* a_g1 = (const float*)d_in[7],  *a_be1 = (const float*)d_in[8];
  const float* a_w2 = (const float*)d_in[9],  *a_b2  = (const float*)d_in[10];
  const float* a_g2 = (const float*)d_in[11], *a_be2 = (const float*)d_in[12];
  const float* a_w3 = (const float*)d_in[13], *a_b3  = (const float*)d_in[14];
  const float* c_w1 = (const float*)d_in[15], *c_b1  = (const float*)d_in[16];
  const float* c_g1 = (const float*)d_in[17], *c_be1 = (const float*)d_in[18];
  const float* c_w2 = (const float*)d_in[19], *c_b2  = (const float*)d_in[20];
  const float* c_g2 = (const float*)d_in[21], *c_be2 = (const float*)d_in[22];
  const float* c_w3 = (const float*)d_in[23], *c_b3  = (const float*)d_in[24];
  const float* mw1  = (const float*)d_in[25], *mb1   = (const float*)d_in[26];
  const float* mw2  = (const float*)d_in[27], *mb2   = (const float*)d_in[28];
  float* out = (float*)d_out;

  char* pp = (char*)d_ws;
  auto alloc = [&](size_t b)->char*{ char* r = pp; pp += (b + 255) & ~(size_t)255; return r; };

  const size_t CH = (size_t)NN * 2;
  char* R = alloc(2304 * CH);                      // 92.16 MB
  float* dinv = (float*)alloc((size_t)NN * 4);
  int* deg    = (int*)alloc((size_t)NN * 4);
  int* offs   = (int*)alloc((size_t)(NN + 1) * 4);
  int* cur    = (int*)alloc((size_t)NN * 4);
  int* srcs   = (int*)alloc((size_t)NE * 4);
  int* startg = (int*)alloc((size_t)(NG + 1) * 4);
  float* sacc = (float*)alloc(2048 * 4);
  float* s2acc = sacc + 1024;
  float* scv  = (float*)alloc(1024 * 4);
  float* shv  = (float*)alloc(1024 * 4);
  u16* WT  = (u16*)alloc(2162688 * 2);             // 4.33 MB
  u16* wt0  = WT;                // 256x128
  u16* wtA1 = WT + 32768;        // 384x256
  u16* wtA2 = WT + 131072;       // 512x384
  u16* wtA3 = WT + 327680;       // 512x256
  u16* wtC1 = WT + 458752;       // 768x512
  u16* wtC2 = WT + 851968;       // 1024x768
  u16* wtC3 = WT + 1638400;      // 1024x512
  float* P  = (float*)WT;
  float* Hh = P + (size_t)NG * 1024;

  auto slot = [&](int s)->u16*{ return (u16*)(R + (size_t)s * CH); };
  u16* xb  = slot(512);
  u16* ax  = slot(0);
  u16* h0  = slot(128);
  u16* ah0 = slot(1664);
  u16* t1  = slot(1920);
  u16* at  = slot(1280);
  u16* h1  = slot(768);
  u16* ah1 = slot(1792);
  u16* u1  = slot(0);
  u16* au  = slot(1024);
  u16* h2  = slot(0);

  auto cdiv = [](int a, int b){ return (a + b - 1) / b; };

  // graph preprocessing
  k_zero<<<cdiv(NN,256),256,0,stream>>>(deg, NN);
  k_zero<<<cdiv(NN,256),256,0,stream>>>(cur, NN);
  k_deg <<<cdiv(NE,256),256,0,stream>>>(ei, deg);
  k_dinv<<<cdiv(NN,256),256,0,stream>>>(deg, dinv);
  k_scan<<<1,1024,0,stream>>>(deg, offs);
  k_fill<<<cdiv(NE,256),256,0,stream>>>(ei, offs, cur, srcs);
  k_bounds<<<cdiv(NN,256),256,0,stream>>>(bat, startg);
  k_cast<<<cdiv(NN*32,256),256,0,stream>>>((const float4*)x, (ushort4*)xb, NN*32);

  // weight prep (fp32 [K,N] -> bf16 [N,K])
  k_wprep<<<dim3(2,4),  256,0,stream>>>(w0,   wt0,  128, 256);
  k_wprep<<<dim3(4,6),  256,0,stream>>>(a_w1, wtA1, 256, 384);
  k_wprep<<<dim3(6,8),  256,0,stream>>>(a_w2, wtA2, 384, 512);
  k_wprep<<<dim3(4,8),  256,0,stream>>>(a_w3, wtA3, 256, 512);
  k_wprep<<<dim3(8,12), 256,0,stream>>>(c_w1, wtC1, 512, 768);
  k_wprep<<<dim3(12,16),256,0,stream>>>(c_w2, wtC2, 768, 1024);
  k_wprep<<<dim3(8,16), 256,0,stream>>>(c_w3, wtC3, 512, 1024);

  auto agg = [&](const u16* in, u16* o, int C){
    int C8 = C / 8;
    int gb = cdiv(NN * C8, 256);
    switch (C8){
      case 16: k_agg_b<16><<<gb,256,0,stream>>>((const uint4*)in,(uint4*)o,dinv,offs,srcs); break;
      case 32: k_agg_b<32><<<gb,256,0,stream>>>((const uint4*)in,(uint4*)o,dinv,offs,srcs); break;
      case 48: k_agg_b<48><<<gb,256,0,stream>>>((const uint4*)in,(uint4*)o,dinv,offs,srcs); break;
      case 64: k_agg_b<64><<<gb,256,0,stream>>>((const uint4*)in,(uint4*)o,dinv,offs,srcs); break;
      case 96: k_agg_b<96><<<gb,256,0,stream>>>((const uint4*)in,(uint4*)o,dinv,offs,srcs); break;
      default: break;
    }
  };
  // mode: 0=bias, 1=bias+relu, 2=bias+add ; stats: fuse BN sum/sumsq (mode 0 only)
  auto gemm_m = [&](const u16* A, const u16* BT_, const float* bi, u16* Cc,
                    int K, int Nc, int mode, bool stats){
    dim3 g(cdiv(NN,128), Nc/128);
    if (stats){
      k_zero<<<cdiv(2048,256),256,0,stream>>>((int*)sacc, 2048);
      k_mfma<0,true><<<g,256,0,stream>>>(A, BT_, bi, Cc, sacc, s2acc, NN, K, Nc);
    } else if (mode == 0)
      k_mfma<0,false><<<g,256,0,stream>>>(A, BT_, bi, Cc, nullptr, nullptr, NN, K, Nc);
    else if (mode == 1)
      k_mfma<1,false><<<g,256,0,stream>>>(A, BT_, bi, Cc, nullptr, nullptr, NN, K, Nc);
    else
      k_mfma<2,false><<<g,256,0,stream>>>(A, BT_, bi, Cc, nullptr, nullptr, NN, K, Nc);
  };
  auto bn = [&](u16* raw, const float* g, const float* be, int C){
    k_bnfin<<<cdiv(C,256),256,0,stream>>>(sacc, s2acc, g, be, scv, shv, C);
    int total = NN * (C / 4);
    k_bnapply_b<<<cdiv(total,256),256,0,stream>>>((const ushort4*)raw, scv, shv,
                                                  (ushort4*)raw, C/4, total);
  };

  // stem
  agg(xb, ax, 128);
  gemm_m(ax, wt0, b0, h0, 128, 256, 1, false);
  // block0 (256 -> 384 -> 512)
  agg(h0, ah0, 256);
  gemm_m(ah0, wtA1, a_b1, t1, 256, 384, 0, true);    // t1raw + stats
  bn(t1, a_g1, a_be1, 384);
  agg(t1, at, 384);
  gemm_m(at, wtA2, a_b2, h1, 384, 512, 0, true);     // t2raw + stats
  bn(h1, a_g2, a_be2, 512);
  gemm_m(ah0, wtA3, a_b3, h1, 256, 512, 2, false);   // h1 += ah0@w3+b3
  // block1 (512 -> 768 -> 1024)
  agg(h1, ah1, 512);
  gemm_m(ah1, wtC1, c_b1, u1, 512, 768, 0, true);    // u1raw + stats
  bn(u1, c_g1, c_be1, 768);
  agg(u1, au, 768);
  gemm_m(au, wtC2, c_b2, h2, 768, 1024, 0, true);    // u2raw + stats
  bn(h2, c_g2, c_be2, 1024);
  gemm_m(ah1, wtC3, c_b3, h2, 512, 1024, 2, false);  // h2 += ah1@c_w3+c_b3
  // pool + MLP (fp32)
  k_pool_b<<<NG,256,0,stream>>>(h2, startg, P);
  {
    dim3 g1(cdiv(NG,64), 1024/64);
    k_gemm<true><<<g1,256,0,stream>>>(P, mw1, mb1, Hh, NG, 1024, 1024);
    dim3 g2(cdiv(NG,64), 768/64);
    k_gemm<false><<<g2,256,0,stream>>>(Hh, mw2, mb2, out, NG, 1024, 768);
  }
}

// Round 6
// 838.131 us; speedup vs baseline: 2.4530x; 1.0930x over previous
//
#include <hip/hip_runtime.h>
#include <cstdint>
#include <cstddef>

#define NN 20000
#define NE 320000
#define NG 256

typedef unsigned short u16;
typedef __attribute__((ext_vector_type(8))) short bf16x8;
typedef __attribute__((ext_vector_type(4))) float f32x4;

// ---------------- bf16 helpers (storage bf16, math fp32) ----------------
__device__ inline float b2f(u16 h){
  union { unsigned u; float f; } v; v.u = ((unsigned)h) << 16; return v.f;
}
__device__ inline u16 f2b(float f){
  union { float f; unsigned u; } v; v.f = f;
  unsigned r = v.u + 0x7FFFu + ((v.u >> 16) & 1u);   // round-nearest-even
  return (u16)(r >> 16);
}
__device__ inline void up8(const uint4& v, float* a){
  union { unsigned u; float f; } t;
  t.u = v.x << 16;         a[0] = t.f;
  t.u = v.x & 0xffff0000u; a[1] = t.f;
  t.u = v.y << 16;         a[2] = t.f;
  t.u = v.y & 0xffff0000u; a[3] = t.f;
  t.u = v.z << 16;         a[4] = t.f;
  t.u = v.z & 0xffff0000u; a[5] = t.f;
  t.u = v.w << 16;         a[6] = t.f;
  t.u = v.w & 0xffff0000u; a[7] = t.f;
}
__device__ inline unsigned pk2(float a, float b){
  return (unsigned)f2b(a) | (((unsigned)f2b(b)) << 16);
}
__device__ inline void bnrelu8(float* b, const float* sc, const float* sh){
  #pragma unroll
  for (int k = 0; k < 8; k++) b[k] = fmaxf(fmaf(b[k], sc[k], sh[k]), 0.f);
}

__device__ inline void gload_lds16(const void* g, void* l){
  __builtin_amdgcn_global_load_lds(
      (const __attribute__((address_space(1))) unsigned int*)g,
      (__attribute__((address_space(3))) unsigned int*)l, 16, 0, 0);
}

// ---------------- utility kernels ----------------

__global__ void k_zero(int* __restrict__ p, int n){
  int i = blockIdx.x*blockDim.x + threadIdx.x;
  if (i < n) p[i] = 0;
}

__global__ void k_deg(const int* __restrict__ ei, int* __restrict__ deg){
  int e = blockIdx.x*blockDim.x + threadIdx.x;
  if (e < NE) atomicAdd(&deg[ei[NE + e]], 1);   // dst = ei[1][e]
}

__global__ void k_dinv(const int* __restrict__ deg, float* __restrict__ dinv){
  int i = blockIdx.x*blockDim.x + threadIdx.x;
  if (i < NN) dinv[i] = rsqrtf(1.0f + (float)deg[i]);
}

__global__ void k_scan(const int* __restrict__ counts, int* __restrict__ offs){
  __shared__ int sm[1024];
  int tid = threadIdx.x;
  int carry = 0;
  for (int base = 0; base < NN; base += 1024){
    int idx = base + tid;
    int v = (idx < NN) ? counts[idx] : 0;
    sm[tid] = v;
    __syncthreads();
    for (int d = 1; d < 1024; d <<= 1){
      int t = (tid >= d) ? sm[tid - d] : 0;
      __syncthreads();
      sm[tid] += t;
      __syncthreads();
    }
    int incl = sm[tid];
    if (idx < NN) offs[idx] = carry + incl - v;
    int total = sm[1023];
    __syncthreads();
    carry += total;
  }
  if (tid == 0) offs[NN] = carry;
}

__global__ void k_fill(const int* __restrict__ ei, const int* __restrict__ offs,
                       int* __restrict__ cur, int* __restrict__ srcs){
  int e = blockIdx.x*blockDim.x + threadIdx.x;
  if (e < NE){
    int s = ei[e];
    int d = ei[NE + e];
    int p = atomicAdd(&cur[d], 1);
    srcs[offs[d] + p] = s;
  }
}

__global__ void k_bounds(const int* __restrict__ batch, int* __restrict__ start){
  int i = blockIdx.x*blockDim.x + threadIdx.x;
  if (i < NN){
    int b  = batch[i];
    int bp = (i == 0) ? -1 : batch[i-1];
    for (int g = bp + 1; g <= b; g++) start[g] = i;
    if (i == NN - 1){
      for (int g = b + 1; g <= NG; g++) start[g] = NN;
    }
  }
}

__global__ void k_cast(const float4* __restrict__ x, ushort4* __restrict__ xb, int total4){
  int t = blockIdx.x*blockDim.x + threadIdx.x;
  if (t >= total4) return;
  float4 v = x[t];
  ushort4 o; o.x = f2b(v.x); o.y = f2b(v.y); o.z = f2b(v.z); o.w = f2b(v.w);
  xb[t] = o;
}

// weight prep: fp32 [K,N] row-major -> bf16 [N,K] row-major (tiled transpose)
__global__ __launch_bounds__(256) void k_wprep(const float* __restrict__ w,
                                               u16* __restrict__ wt, int K, int N){
  __shared__ float sm[64][65];
  int kb = blockIdx.x * 64, nb = blockIdx.y * 64;
  int tid = threadIdx.x;
  #pragma unroll
  for (int i = 0; i < 16; i++){
    int t = i*256 + tid;
    int r = t >> 6, c = t & 63;
    sm[r][c] = w[(size_t)(kb + r) * N + nb + c];
  }
  __syncthreads();
  #pragma unroll
  for (int i = 0; i < 16; i++){
    int t = i*256 + tid;
    int r = t >> 6, c = t & 63;
    wt[(size_t)(nb + r) * K + kb + c] = f2b(sm[c][r]);
  }
}

// ---------------- aggregation (bf16 in/out, fp32 accumulate) ----------------
// out[i] = dinv[i] * ( dinv[i]*T(in[i]) + sum_{s in nbr(i)} dinv[s]*T(in[s]) )
// T(x) = BN ? relu(sc*x+sh) : x.  4x edge unroll for memory-level parallelism.
template<int C8, bool BN>
__global__ void k_agg_b(const uint4* __restrict__ in, uint4* __restrict__ out,
                        const float* __restrict__ dinv, const int* __restrict__ offs,
                        const int* __restrict__ srcs,
                        const float* __restrict__ scv, const float* __restrict__ shv){
  int t = blockIdx.x*blockDim.x + threadIdx.x;
  if (t >= NN * C8) return;
  int i = t / C8;
  int c = t - i * C8;
  float sc[8], sh[8];
  if (BN){
    float4 s0 = ((const float4*)scv)[c*2], s1 = ((const float4*)scv)[c*2+1];
    float4 h0 = ((const float4*)shv)[c*2], h1 = ((const float4*)shv)[c*2+1];
    sc[0]=s0.x; sc[1]=s0.y; sc[2]=s0.z; sc[3]=s0.w;
    sc[4]=s1.x; sc[5]=s1.y; sc[6]=s1.z; sc[7]=s1.w;
    sh[0]=h0.x; sh[1]=h0.y; sh[2]=h0.z; sh[3]=h0.w;
    sh[4]=h1.x; sh[5]=h1.y; sh[6]=h1.z; sh[7]=h1.w;
  }
  float di = dinv[i];
  float a[8], acc[8];
  up8(in[t], a);
  if (BN) bnrelu8(a, sc, sh);
  #pragma unroll
  for (int k = 0; k < 8; k++) acc[k] = a[k] * di;

  int e = offs[i], e1 = offs[i + 1];
  for (; e + 4 <= e1; e += 4){
    int sA = srcs[e], sB = srcs[e+1], sC = srcs[e+2], sD = srcs[e+3];
    float dA = dinv[sA], dB = dinv[sB], dC = dinv[sC], dD = dinv[sD];
    uint4 yA = in[(size_t)sA * C8 + c];
    uint4 yB = in[(size_t)sB * C8 + c];
    uint4 yC = in[(size_t)sC * C8 + c];
    uint4 yD = in[(size_t)sD * C8 + c];
    float b[8];
    up8(yA, b);
    if (BN) bnrelu8(b, sc, sh);
    #pragma unroll
    for (int k = 0; k < 8; k++) acc[k] = fmaf(b[k], dA, acc[k]);
    up8(yB, b);
    if (BN) bnrelu8(b, sc, sh);
    #pragma unroll
    for (int k = 0; k < 8; k++) acc[k] = fmaf(b[k], dB, acc[k]);
    up8(yC, b);
    if (BN) bnrelu8(b, sc, sh);
    #pragma unroll
    for (int k = 0; k < 8; k++) acc[k] = fmaf(b[k], dC, acc[k]);
    up8(yD, b);
    if (BN) bnrelu8(b, sc, sh);
    #pragma unroll
    for (int k = 0; k < 8; k++) acc[k] = fmaf(b[k], dD, acc[k]);
  }
  for (; e < e1; e++){
    int s = srcs[e];
    float ds = dinv[s];
    float b[8];
    up8(in[(size_t)s * C8 + c], b);
    if (BN) bnrelu8(b, sc, sh);
    #pragma unroll
    for (int k = 0; k < 8; k++) acc[k] = fmaf(b[k], ds, acc[k]);
  }
  #pragma unroll
  for (int k = 0; k < 8; k++) acc[k] *= di;
  uint4 o;
  o.x = pk2(acc[0], acc[1]); o.y = pk2(acc[2], acc[3]);
  o.z = pk2(acc[4], acc[5]); o.w = pk2(acc[6], acc[7]);
  out[t] = o;
}

// ---------------- MFMA GEMM: A bf16 [M,K], BT bf16 [N,K], C bf16 [M,N] ----------------
// 128x128 tile, BK=64, 256 threads (4 waves, 2x2), 4x4 16x16x32 frags/wave.
// MODE: 0=bias, 1=bias+relu, 2=bias+add-into-C,
//       3=bias + relu(p0*C_old+p1) add (fused BN-apply + skip; p0/p1 = scale/shift)
// STATS: accumulate per-column sum/sumsq of (acc+bias) into p0/p1 (BN stats fusion)
template<int MODE, bool STATS>
__global__ __launch_bounds__(256, 2) void k_mfma(const u16* __restrict__ A,
                                                 const u16* __restrict__ BT,
                                                 const float* __restrict__ bias,
                                                 u16* __restrict__ C,
                                                 float* __restrict__ p0,
                                                 float* __restrict__ p1,
                                                 int M, int K, int Nc){
  __shared__ u16 As[128*64];
  __shared__ u16 Bs[128*64];
  const int tid = threadIdx.x;
  const int lane = tid & 63;
  const int quad = lane >> 4;
  const int l16 = lane & 15;
  const int wid = tid >> 6;
  const int wm = wid & 1, wn = wid >> 1;
  const int bm = blockIdx.x * 128, bn = blockIdx.y * 128;

  f32x4 acc[4][4];
  #pragma unroll
  for (int i = 0; i < 4; i++)
    #pragma unroll
    for (int j = 0; j < 4; j++)
      acc[i][j] = (f32x4){0.f, 0.f, 0.f, 0.f};

  const int srow = tid >> 3;
  const int scol8 = tid & 7;
  for (int k0 = 0; k0 < K; k0 += 64){
    #pragma unroll
    for (int i = 0; i < 4; i++){
      int row = i*32 + srow;
      int gc = (scol8 ^ (row & 7)) * 8;
      int lofs = row*64 + scol8*8;
      gload_lds16(A + (size_t)(bm + row) * K + k0 + gc, As + lofs);
      gload_lds16(BT + (size_t)(bn + row) * K + k0 + gc, Bs + lofs);
    }
    __syncthreads();
    #pragma unroll
    for (int kk = 0; kk < 2; kk++){
      const int col8 = kk*4 + quad;
      bf16x8 af[4], bfr[4];
      #pragma unroll
      for (int mi = 0; mi < 4; mi++){
        int row = wm*64 + mi*16 + l16;
        af[mi] = *(const bf16x8*)(As + row*64 + ((col8 ^ (row & 7)) * 8));
      }
      #pragma unroll
      for (int ni = 0; ni < 4; ni++){
        int row = wn*64 + ni*16 + l16;
        bfr[ni] = *(const bf16x8*)(Bs + row*64 + ((col8 ^ (row & 7)) * 8));
      }
      #pragma unroll
      for (int mi = 0; mi < 4; mi++)
        #pragma unroll
        for (int ni = 0; ni < 4; ni++)
          acc[mi][ni] = __builtin_amdgcn_mfma_f32_16x16x32_bf16(af[mi], bfr[ni], acc[mi][ni], 0, 0, 0);
    }
    __syncthreads();
  }
  // epilogue: C/D layout col=lane&15, row=quad*4+reg
  #pragma unroll
  for (int ni = 0; ni < 4; ni++){
    int col = bn + wn*64 + ni*16 + l16;
    float bb = bias[col];
    float bsc = 0.f, bsh = 0.f;
    if (MODE == 3){ bsc = p0[col]; bsh = p1[col]; }
    float s = 0.f, s2 = 0.f;
    #pragma unroll
    for (int mi = 0; mi < 4; mi++){
      int rbase = bm + wm*64 + mi*16 + quad*4;
      #pragma unroll
      for (int r = 0; r < 4; r++){
        int row = rbase + r;
        if (row < M){
          float v = acc[mi][ni][r] + bb;
          if (STATS){ s += v; s2 += v * v; }
          if (MODE == 1) v = fmaxf(v, 0.f);
          u16* cp = C + (size_t)row * Nc + col;
          if (MODE == 2) v += b2f(*cp);
          if (MODE == 3) v += fmaxf(fmaf(b2f(*cp), bsc, bsh), 0.f);
          *cp = f2b(v);
        }
      }
    }
    if (STATS){
      s  += __shfl_xor(s, 16, 64);  s  += __shfl_xor(s, 32, 64);
      s2 += __shfl_xor(s2, 16, 64); s2 += __shfl_xor(s2, 32, 64);
      if (quad == 0){
        atomicAdd(&p0[col], s);
        atomicAdd(&p1[col], s2);
      }
    }
  }
}

// ---------------- fp32 GEMM (MLP tail, small M) ----------------
template<bool RELU>
__global__ __launch_bounds__(256) void k_gemm(const float* __restrict__ A,
                                              const float* __restrict__ B,
                                              const float* __restrict__ bias,
                                              float* __restrict__ C,
                                              int M, int K, int Nc){
  __shared__ float As[16][68];
  __shared__ float Bs[16][64];
  const int tid = threadIdx.x;
  const int tx = tid & 15, ty = tid >> 4;
  const int bm = blockIdx.x * 64, bn = blockIdx.y * 64;
  const int arow = tid >> 2, akq = (tid & 3) << 2;
  const int brow = tid >> 4, bcol = (tid & 15) << 2;
  float acc[4][4] = {{0.f}};
  const bool aval = (bm + arow) < M;
  const float* Aptr = A + (size_t)(bm + arow) * K + akq;
  const float* Bptr = B + (size_t)brow * Nc + bn + bcol;
  for (int k0 = 0; k0 < K; k0 += 16){
    float4 av = make_float4(0.f, 0.f, 0.f, 0.f);
    if (aval) av = *(const float4*)(Aptr + k0);
    float4 bv = *(const float4*)(Bptr + (size_t)k0 * Nc);
    As[akq + 0][arow] = av.x;
    As[akq + 1][arow] = av.y;
    As[akq + 2][arow] = av.z;
    As[akq + 3][arow] = av.w;
    *(float4*)&Bs[brow][bcol] = bv;
    __syncthreads();
    #pragma unroll
    for (int kk = 0; kk < 16; kk++){
      const float4 a = *(const float4*)(&As[kk][ty << 2]);
      const float4 b = *(const float4*)(&Bs[kk][tx << 2]);
      const float ar[4] = {a.x, a.y, a.z, a.w};
      const float br[4] = {b.x, b.y, b.z, b.w};
      #pragma unroll
      for (int i = 0; i < 4; i++)
        #pragma unroll
        for (int j = 0; j < 4; j++)
          acc[i][j] = fmaf(ar[i], br[j], acc[i][j]);
    }
    __syncthreads();
  }
  const int col = bn + (tx << 2);
  const float4 bb = *(const float4*)(bias + col);
  #pragma unroll
  for (int i = 0; i < 4; i++){
    int row = bm + (ty << 2) + i;
    if (row < M){
      float4 o;
      o.x = acc[i][0] + bb.x;
      o.y = acc[i][1] + bb.y;
      o.z = acc[i][2] + bb.z;
      o.w = acc[i][3] + bb.w;
      if (RELU){
        o.x = fmaxf(o.x, 0.f); o.y = fmaxf(o.y, 0.f);
        o.z = fmaxf(o.z, 0.f); o.w = fmaxf(o.w, 0.f);
      }
      *(float4*)(C + (size_t)row * Nc + col) = o;
    }
  }
}

// ---------------- BatchNorm finalize ----------------

__global__ void k_bnfin(const float* __restrict__ sacc, const float* __restrict__ s2acc,
                        const float* __restrict__ g, const float* __restrict__ be,
                        float* __restrict__ scale, float* __restrict__ shift, int C){
  int c = blockIdx.x * blockDim.x + threadIdx.x;
  if (c >= C) return;
  float m = sacc[c] * (1.0f / NN);
  float v = s2acc[c] * (1.0f / NN) - m * m;
  float rs = rsqrtf(v + 1e-5f);
  float sc = g[c] * rs;
  scale[c] = sc;
  shift[c] = be[c] - m * sc;
}

// ---------------- mean pool: h2 bf16 [NN,1024] -> pooled fp32 [NG,1024] ----------------
__global__ void k_pool_b(const u16* __restrict__ h, const int* __restrict__ start,
                         float* __restrict__ pooled){
  int g = blockIdx.x;
  int c = threadIdx.x << 2;
  int r0 = start[g], r1 = start[g + 1];
  float a0 = 0.f, a1 = 0.f, a2 = 0.f, a3 = 0.f;
  for (int r = r0; r < r1; r++){
    ushort4 v = *(const ushort4*)(h + (size_t)r * 1024 + c);
    a0 += b2f(v.x); a1 += b2f(v.y); a2 += b2f(v.z); a3 += b2f(v.w);
  }
  float inv = (r1 > r0) ? (1.0f / (float)(r1 - r0)) : 0.0f;
  float4 o; o.x = a0 * inv; o.y = a1 * inv; o.z = a2 * inv; o.w = a3 * inv;
  *(float4*)(pooled + (size_t)g * 1024 + c) = o;
}

// ---------------- host launcher ----------------

extern "C" void kernel_launch(void* const* d_in, const int* in_sizes, int n_in,
                              void* d_out, int out_size, void* d_ws, size_t ws_size,
                              hipStream_t stream) {
  const float* x    = (const float*)d_in[0];
  const int*   ei   = (const int*)d_in[1];
  const int*   bat  = (const int*)d_in[2];
  const float* w0   = (const float*)d_in[3];
  const float* b0   = (const float*)d_in[4];
  const float* a_w1 = (const float*)d_in[5],  *a_b1  = (const float*)d_in[6];
  const float* a_g1 = (const float*)d_in[7],  *a_be1 = (const float*)d_in[8];
  const float* a_w2 = (const float*)d_in[9],  *a_b2  = (const float*)d_in[10];
  const float* a_g2 = (const float*)d_in[11], *a_be2 = (const float*)d_in[12];
  const float* a_w3 = (const float*)d_in[13], *a_b3  = (const float*)d_in[14];
  const float* c_w1 = (const float*)d_in[15], *c_b1  = (const float*)d_in[16];
  const float* c_g1 = (const float*)d_in[17], *c_be1 = (const float*)d_in[18];
  const float* c_w2 = (const float*)d_in[19], *c_b2  = (const float*)d_in[20];
  const float* c_g2 = (const float*)d_in[21], *c_be2 = (const float*)d_in[22];
  const float* c_w3 = (const float*)d_in[23], *c_b3  = (const float*)d_in[24];
  const float* mw1  = (const float*)d_in[25], *mb1   = (const float*)d_in[26];
  const float* mw2  = (const float*)d_in[27], *mb2   = (const float*)d_in[28];
  float* out = (float*)d_out;

  char* pp = (char*)d_ws;
  auto alloc = [&](size_t b)->char*{ char* r = pp; pp += (b + 255) & ~(size_t)255; return r; };

  const size_t CH = (size_t)NN * 2;
  char* R = alloc(2304 * CH);                      // 92.16 MB
  float* dinv = (float*)alloc((size_t)NN * 4);
  int* deg    = (int*)alloc((size_t)NN * 4);
  int* offs   = (int*)alloc((size_t)(NN + 1) * 4);
  int* cur    = (int*)alloc((size_t)NN * 4);
  int* srcs   = (int*)alloc((size_t)NE * 4);
  int* startg = (int*)alloc((size_t)(NG + 1) * 4);
  float* sacc = (float*)alloc(2048 * 4);
  float* s2acc = sacc + 1024;
  float* scv  = (float*)alloc(1024 * 4);
  float* shv  = (float*)alloc(1024 * 4);
  u16* WT  = (u16*)alloc(2162688 * 2);             // 4.33 MB
  u16* wt0  = WT;                // 256x128
  u16* wtA1 = WT + 32768;        // 384x256
  u16* wtA2 = WT + 131072;       // 512x384
  u16* wtA3 = WT + 327680;       // 512x256
  u16* wtC1 = WT + 458752;       // 768x512
  u16* wtC2 = WT + 851968;       // 1024x768
  u16* wtC3 = WT + 1638400;      // 1024x512
  float* P  = (float*)WT;
  float* Hh = P + (size_t)NG * 1024;

  auto slot = [&](int s)->u16*{ return (u16*)(R + (size_t)s * CH); };
  u16* xb  = slot(512);
  u16* ax  = slot(0);
  u16* h0  = slot(128);
  u16* ah0 = slot(1664);
  u16* t1  = slot(1920);
  u16* at  = slot(1280);
  u16* h1  = slot(768);
  u16* ah1 = slot(1792);
  u16* u1  = slot(0);
  u16* au  = slot(1024);
  u16* h2  = slot(0);

  auto cdiv = [](int a, int b){ return (a + b - 1) / b; };

  // graph preprocessing
  k_zero<<<cdiv(NN,256),256,0,stream>>>(deg, NN);
  k_zero<<<cdiv(NN,256),256,0,stream>>>(cur, NN);
  k_deg <<<cdiv(NE,256),256,0,stream>>>(ei, deg);
  k_dinv<<<cdiv(NN,256),256,0,stream>>>(deg, dinv);
  k_scan<<<1,1024,0,stream>>>(deg, offs);
  k_fill<<<cdiv(NE,256),256,0,stream>>>(ei, offs, cur, srcs);
  k_bounds<<<cdiv(NN,256),256,0,stream>>>(bat, startg);
  k_cast<<<cdiv(NN*32,256),256,0,stream>>>((const float4*)x, (ushort4*)xb, NN*32);

  // weight prep (fp32 [K,N] -> bf16 [N,K])
  k_wprep<<<dim3(2,4),  256,0,stream>>>(w0,   wt0,  128, 256);
  k_wprep<<<dim3(4,6),  256,0,stream>>>(a_w1, wtA1, 256, 384);
  k_wprep<<<dim3(6,8),  256,0,stream>>>(a_w2, wtA2, 384, 512);
  k_wprep<<<dim3(4,8),  256,0,stream>>>(a_w3, wtA3, 256, 512);
  k_wprep<<<dim3(8,12), 256,0,stream>>>(c_w1, wtC1, 512, 768);
  k_wprep<<<dim3(12,16),256,0,stream>>>(c_w2, wtC2, 768, 1024);
  k_wprep<<<dim3(8,16), 256,0,stream>>>(c_w3, wtC3, 512, 1024);

  // agg: plain (BN=false) or BN-fused input transform (BN=true, uses scv/shv)
  auto agg = [&](const u16* in, u16* o, int C, bool bnf){
    int C8 = C / 8;
    int gb = cdiv(NN * C8, 256);
    if (!bnf){
      switch (C8){
        case 16: k_agg_b<16,false><<<gb,256,0,stream>>>((const uint4*)in,(uint4*)o,dinv,offs,srcs,nullptr,nullptr); break;
        case 32: k_agg_b<32,false><<<gb,256,0,stream>>>((const uint4*)in,(uint4*)o,dinv,offs,srcs,nullptr,nullptr); break;
        case 64: k_agg_b<64,false><<<gb,256,0,stream>>>((const uint4*)in,(uint4*)o,dinv,offs,srcs,nullptr,nullptr); break;
        default: break;
      }
    } else {
      switch (C8){
        case 48: k_agg_b<48,true><<<gb,256,0,stream>>>((const uint4*)in,(uint4*)o,dinv,offs,srcs,scv,shv); break;
        case 96: k_agg_b<96,true><<<gb,256,0,stream>>>((const uint4*)in,(uint4*)o,dinv,offs,srcs,scv,shv); break;
        default: break;
      }
    }
  };
  // mode: 0=bias, 1=bias+relu, 2=bias+add, 3=bias + relu(sc*C_old+sh) add
  auto gemm_m = [&](const u16* A, const u16* BT_, const float* bi, u16* Cc,
                    int K, int Nc, int mode, bool stats){
    dim3 g(cdiv(NN,128), Nc/128);
    if (stats){
      k_zero<<<cdiv(2048,256),256,0,stream>>>((int*)sacc, 2048);
      k_mfma<0,true><<<g,256,0,stream>>>(A, BT_, bi, Cc, sacc, s2acc, NN, K, Nc);
    } else if (mode == 0)
      k_mfma<0,false><<<g,256,0,stream>>>(A, BT_, bi, Cc, nullptr, nullptr, NN, K, Nc);
    else if (mode == 1)
      k_mfma<1,false><<<g,256,0,stream>>>(A, BT_, bi, Cc, nullptr, nullptr, NN, K, Nc);
    else if (mode == 2)
      k_mfma<2,false><<<g,256,0,stream>>>(A, BT_, bi, Cc, nullptr, nullptr, NN, K, Nc);
    else
      k_mfma<3,false><<<g,256,0,stream>>>(A, BT_, bi, Cc, scv, shv, NN, K, Nc);
  };
  auto bnfin = [&](const float* g, const float* be, int C){
    k_bnfin<<<cdiv(C,256),256,0,stream>>>(sacc, s2acc, g, be, scv, shv, C);
  };

  // stem
  agg(xb, ax, 128, false);
  gemm_m(ax, wt0, b0, h0, 128, 256, 1, false);
  // block0 (256 -> 384 -> 512)
  agg(h0, ah0, 256, false);
  gemm_m(ah0, wtA1, a_b1, t1, 256, 384, 0, true);    // t1raw + stats
  bnfin(a_g1, a_be1, 384);
  agg(t1, at, 384, true);                            // at = agg(relu(bn(t1raw)))
  gemm_m(at, wtA2, a_b2, h1, 384, 512, 0, true);     // t2raw + stats
  bnfin(a_g2, a_be2, 512);
  gemm_m(ah0, wtA3, a_b3, h1, 256, 512, 3, false);   // h1 = relu(bn(t2raw)) + ah0@w3+b3
  // block1 (512 -> 768 -> 1024)
  agg(h1, ah1, 512, false);
  gemm_m(ah1, wtC1, c_b1, u1, 512, 768, 0, true);    // u1raw + stats
  bnfin(c_g1, c_be1, 768);
  agg(u1, au, 768, true);                            // au = agg(relu(bn(u1raw)))
  gemm_m(au, wtC2, c_b2, h2, 768, 1024, 0, true);    // u2raw + stats
  bnfin(c_g2, c_be2, 1024);
  gemm_m(ah1, wtC3, c_b3, h2, 512, 1024, 3, false);  // h2 = relu(bn(u2raw)) + ah1@c_w3+c_b3
  // pool + MLP (fp32)
  k_pool_b<<<NG,256,0,stream>>>(h2, startg, P);
  {
    dim3 g1(cdiv(NG,64), 1024/64);
    k_gemm<true><<<g1,256,0,stream>>>(P, mw1, mb1, Hh, NG, 1024, 1024);
    dim3 g2(cdiv(NG,64), 768/64);
    k_gemm<false><<<g2,256,0,stream>>>(Hh, mw2, mb2, out, NG, 1024, 768);
  }
}

// Round 7
// 794.413 us; speedup vs baseline: 2.5880x; 1.0550x over previous
//
#include <hip/hip_runtime.h>
#include <cstdint>
#include <cstddef>

#define NN 20000
#define NE 320000
#define NG 256
#define NB 79   // ceil(NN/256)

typedef unsigned short u16;
typedef __attribute__((ext_vector_type(8))) short bf16x8;
typedef __attribute__((ext_vector_type(4))) float f32x4;

// ---------------- bf16 helpers (storage bf16, math fp32) ----------------
__device__ inline float b2f(u16 h){
  union { unsigned u; float f; } v; v.u = ((unsigned)h) << 16; return v.f;
}
__device__ inline u16 f2b(float f){
  union { float f; unsigned u; } v; v.f = f;
  unsigned r = v.u + 0x7FFFu + ((v.u >> 16) & 1u);   // round-nearest-even
  return (u16)(r >> 16);
}
__device__ inline void up8(const uint4& v, float* a){
  union { unsigned u; float f; } t;
  t.u = v.x << 16;         a[0] = t.f;
  t.u = v.x & 0xffff0000u; a[1] = t.f;
  t.u = v.y << 16;         a[2] = t.f;
  t.u = v.y & 0xffff0000u; a[3] = t.f;
  t.u = v.z << 16;         a[4] = t.f;
  t.u = v.z & 0xffff0000u; a[5] = t.f;
  t.u = v.w << 16;         a[6] = t.f;
  t.u = v.w & 0xffff0000u; a[7] = t.f;
}
__device__ inline unsigned pk2(float a, float b){
  return (unsigned)f2b(a) | (((unsigned)f2b(b)) << 16);
}
__device__ inline void bnrelu8(float* b, const float* sc, const float* sh){
  #pragma unroll
  for (int k = 0; k < 8; k++) b[k] = fmaxf(fmaf(b[k], sc[k], sh[k]), 0.f);
}

__device__ inline void gload_lds16(const void* g, void* l){
  __builtin_amdgcn_global_load_lds(
      (const __attribute__((address_space(1))) unsigned int*)g,
      (__attribute__((address_space(3))) unsigned int*)l, 16, 0, 0);
}

// ---------------- utility kernels ----------------

__global__ void k_zero(int* __restrict__ p, int n){
  int i = blockIdx.x*blockDim.x + threadIdx.x;
  if (i < n) p[i] = 0;
}

__global__ void k_deg(const int* __restrict__ ei, int* __restrict__ deg){
  int e = blockIdx.x*blockDim.x + threadIdx.x;
  if (e < NE) atomicAdd(&deg[ei[NE + e]], 1);   // dst = ei[1][e]
}

__global__ void k_dinv(const int* __restrict__ deg, float* __restrict__ dinv){
  int i = blockIdx.x*blockDim.x + threadIdx.x;
  if (i < NN) dinv[i] = rsqrtf(1.0f + (float)deg[i]);
}

// two-level scan: counts[NN] -> offs[NN+1]
__global__ void k_scan1(const int* __restrict__ counts, int* __restrict__ bsum){
  __shared__ int sm[256];
  int b = blockIdx.x, tid = threadIdx.x, idx = b*256 + tid;
  sm[tid] = (idx < NN) ? counts[idx] : 0;
  __syncthreads();
  for (int d = 128; d > 0; d >>= 1){
    if (tid < d) sm[tid] += sm[tid + d];
    __syncthreads();
  }
  if (tid == 0) bsum[b] = sm[0];
}
__global__ void k_scan2(int* __restrict__ bsum){
  if (threadIdx.x == 0){
    int c = 0;
    for (int i = 0; i < NB; i++){ int t = bsum[i]; bsum[i] = c; c += t; }
    bsum[NB] = c;
  }
}
__global__ void k_scan3(const int* __restrict__ counts, const int* __restrict__ bsum,
                        int* __restrict__ offs){
  __shared__ int sm[256];
  int b = blockIdx.x, tid = threadIdx.x, idx = b*256 + tid;
  int v = (idx < NN) ? counts[idx] : 0;
  sm[tid] = v;
  __syncthreads();
  for (int d = 1; d < 256; d <<= 1){
    int t = (tid >= d) ? sm[tid - d] : 0;
    __syncthreads();
    sm[tid] += t;
    __syncthreads();
  }
  if (idx < NN) offs[idx] = bsum[b] + sm[tid] - v;
  if (idx == NN - 1) offs[NN] = bsum[NB];
}

__global__ void k_fill(const int* __restrict__ ei, const int* __restrict__ offs,
                       int* __restrict__ cur, int* __restrict__ srcs){
  int e = blockIdx.x*blockDim.x + threadIdx.x;
  if (e < NE){
    int s = ei[e];
    int d = ei[NE + e];
    int p = atomicAdd(&cur[d], 1);
    srcs[offs[d] + p] = s;
  }
}

__global__ void k_bounds(const int* __restrict__ batch, int* __restrict__ start){
  int i = blockIdx.x*blockDim.x + threadIdx.x;
  if (i < NN){
    int b  = batch[i];
    int bp = (i == 0) ? -1 : batch[i-1];
    for (int g = bp + 1; g <= b; g++) start[g] = i;
    if (i == NN - 1){
      for (int g = b + 1; g <= NG; g++) start[g] = NN;
    }
  }
}

__global__ void k_cast(const float4* __restrict__ x, ushort4* __restrict__ xb, int total4){
  int t = blockIdx.x*blockDim.x + threadIdx.x;
  if (t >= total4) return;
  float4 v = x[t];
  ushort4 o; o.x = f2b(v.x); o.y = f2b(v.y); o.z = f2b(v.z); o.w = f2b(v.w);
  xb[t] = o;
}

// weight prep: fp32 [K,N] row-major -> bf16 [N,K] row-major (tiled transpose)
__global__ __launch_bounds__(256) void k_wprep(const float* __restrict__ w,
                                               u16* __restrict__ wt, int K, int N){
  __shared__ float sm[64][65];
  int kb = blockIdx.x * 64, nb = blockIdx.y * 64;
  int tid = threadIdx.x;
  #pragma unroll
  for (int i = 0; i < 16; i++){
    int t = i*256 + tid;
    int r = t >> 6, c = t & 63;
    sm[r][c] = w[(size_t)(kb + r) * N + nb + c];
  }
  __syncthreads();
  #pragma unroll
  for (int i = 0; i < 16; i++){
    int t = i*256 + tid;
    int r = t >> 6, c = t & 63;
    wt[(size_t)(nb + r) * K + kb + c] = f2b(sm[c][r]);
  }
}

// ---------------- aggregation (bf16 in/out, fp32 accumulate) ----------------
template<int C8, bool BN>
__global__ void k_agg_b(const uint4* __restrict__ in, uint4* __restrict__ out,
                        const float* __restrict__ dinv, const int* __restrict__ offs,
                        const int* __restrict__ srcs,
                        const float* __restrict__ scv, const float* __restrict__ shv){
  int t = blockIdx.x*blockDim.x + threadIdx.x;
  if (t >= NN * C8) return;
  int i = t / C8;
  int c = t - i * C8;
  float sc[8], sh[8];
  if (BN){
    float4 s0 = ((const float4*)scv)[c*2], s1 = ((const float4*)scv)[c*2+1];
    float4 h0 = ((const float4*)shv)[c*2], h1 = ((const float4*)shv)[c*2+1];
    sc[0]=s0.x; sc[1]=s0.y; sc[2]=s0.z; sc[3]=s0.w;
    sc[4]=s1.x; sc[5]=s1.y; sc[6]=s1.z; sc[7]=s1.w;
    sh[0]=h0.x; sh[1]=h0.y; sh[2]=h0.z; sh[3]=h0.w;
    sh[4]=h1.x; sh[5]=h1.y; sh[6]=h1.z; sh[7]=h1.w;
  }
  float di = dinv[i];
  float a[8], acc[8];
  up8(in[t], a);
  if (BN) bnrelu8(a, sc, sh);
  #pragma unroll
  for (int k = 0; k < 8; k++) acc[k] = a[k] * di;

  int e = offs[i], e1 = offs[i + 1];
  for (; e + 4 <= e1; e += 4){
    int sA = srcs[e], sB = srcs[e+1], sC = srcs[e+2], sD = srcs[e+3];
    float dA = dinv[sA], dB = dinv[sB], dC = dinv[sC], dD = dinv[sD];
    uint4 yA = in[(size_t)sA * C8 + c];
    uint4 yB = in[(size_t)sB * C8 + c];
    uint4 yC = in[(size_t)sC * C8 + c];
    uint4 yD = in[(size_t)sD * C8 + c];
    float b[8];
    up8(yA, b);
    if (BN) bnrelu8(b, sc, sh);
    #pragma unroll
    for (int k = 0; k < 8; k++) acc[k] = fmaf(b[k], dA, acc[k]);
    up8(yB, b);
    if (BN) bnrelu8(b, sc, sh);
    #pragma unroll
    for (int k = 0; k < 8; k++) acc[k] = fmaf(b[k], dB, acc[k]);
    up8(yC, b);
    if (BN) bnrelu8(b, sc, sh);
    #pragma unroll
    for (int k = 0; k < 8; k++) acc[k] = fmaf(b[k], dC, acc[k]);
    up8(yD, b);
    if (BN) bnrelu8(b, sc, sh);
    #pragma unroll
    for (int k = 0; k < 8; k++) acc[k] = fmaf(b[k], dD, acc[k]);
  }
  for (; e < e1; e++){
    int s = srcs[e];
    float ds = dinv[s];
    float b[8];
    up8(in[(size_t)s * C8 + c], b);
    if (BN) bnrelu8(b, sc, sh);
    #pragma unroll
    for (int k = 0; k < 8; k++) acc[k] = fmaf(b[k], ds, acc[k]);
  }
  #pragma unroll
  for (int k = 0; k < 8; k++) acc[k] *= di;
  uint4 o;
  o.x = pk2(acc[0], acc[1]); o.y = pk2(acc[2], acc[3]);
  o.z = pk2(acc[4], acc[5]); o.w = pk2(acc[6], acc[7]);
  out[t] = o;
}

// ---------------- MFMA GEMM: A bf16 [M,K], BT bf16 [N,K], C bf16 [M,N] ----------------
// 128x128 tile, BK=64, 256 threads (4 waves, 2x2), 4x4 16x16x32 frags/wave.
// 4 blocks/CU (128 KB LDS) for latency hiding.
// MODE: 0=bias, 1=bias+relu, 2=bias+add-into-C,
//       3=bias + relu(p0*C_old+p1) add (fused BN-apply + skip)
// STATS: accumulate per-column sum/sumsq of (acc+bias) into p0/p1
template<int MODE, bool STATS>
__global__ __launch_bounds__(256, 4) void k_mfma(const u16* __restrict__ A,
                                                 const u16* __restrict__ BT,
                                                 const float* __restrict__ bias,
                                                 u16* __restrict__ C,
                                                 float* __restrict__ p0,
                                                 float* __restrict__ p1,
                                                 int M, int K, int Nc){
  __shared__ u16 As[128*64];
  __shared__ u16 Bs[128*64];
  const int tid = threadIdx.x;
  const int lane = tid & 63;
  const int quad = lane >> 4;
  const int l16 = lane & 15;
  const int wid = tid >> 6;
  const int wm = wid & 1, wn = wid >> 1;
  const int bm = blockIdx.x * 128, bn = blockIdx.y * 128;

  f32x4 acc[4][4];
  #pragma unroll
  for (int i = 0; i < 4; i++)
    #pragma unroll
    for (int j = 0; j < 4; j++)
      acc[i][j] = (f32x4){0.f, 0.f, 0.f, 0.f};

  const int srow = tid >> 3;
  const int scol8 = tid & 7;
  for (int k0 = 0; k0 < K; k0 += 64){
    #pragma unroll
    for (int i = 0; i < 4; i++){
      int row = i*32 + srow;
      int gc = (scol8 ^ (row & 7)) * 8;
      int lofs = row*64 + scol8*8;
      gload_lds16(A + (size_t)(bm + row) * K + k0 + gc, As + lofs);
      gload_lds16(BT + (size_t)(bn + row) * K + k0 + gc, Bs + lofs);
    }
    __syncthreads();
    #pragma unroll
    for (int kk = 0; kk < 2; kk++){
      const int col8 = kk*4 + quad;
      bf16x8 af[4], bfr[4];
      #pragma unroll
      for (int mi = 0; mi < 4; mi++){
        int row = wm*64 + mi*16 + l16;
        af[mi] = *(const bf16x8*)(As + row*64 + ((col8 ^ (row & 7)) * 8));
      }
      #pragma unroll
      for (int ni = 0; ni < 4; ni++){
        int row = wn*64 + ni*16 + l16;
        bfr[ni] = *(const bf16x8*)(Bs + row*64 + ((col8 ^ (row & 7)) * 8));
      }
      #pragma unroll
      for (int mi = 0; mi < 4; mi++)
        #pragma unroll
        for (int ni = 0; ni < 4; ni++)
          acc[mi][ni] = __builtin_amdgcn_mfma_f32_16x16x32_bf16(af[mi], bfr[ni], acc[mi][ni], 0, 0, 0);
    }
    __syncthreads();
  }
  // epilogue: C/D layout col=lane&15, row=quad*4+reg
  #pragma unroll
  for (int ni = 0; ni < 4; ni++){
    int col = bn + wn*64 + ni*16 + l16;
    float bb = bias[col];
    float bsc = 0.f, bsh = 0.f;
    if (MODE == 3){ bsc = p0[col]; bsh = p1[col]; }
    float s = 0.f, s2 = 0.f;
    #pragma unroll
    for (int mi = 0; mi < 4; mi++){
      int rbase = bm + wm*64 + mi*16 + quad*4;
      #pragma unroll
      for (int r = 0; r < 4; r++){
        int row = rbase + r;
        if (row < M){
          float v = acc[mi][ni][r] + bb;
          if (STATS){ s += v; s2 += v * v; }
          if (MODE == 1) v = fmaxf(v, 0.f);
          u16* cp = C + (size_t)row * Nc + col;
          if (MODE == 2) v += b2f(*cp);
          if (MODE == 3) v += fmaxf(fmaf(b2f(*cp), bsc, bsh), 0.f);
          *cp = f2b(v);
        }
      }
    }
    if (STATS){
      s  += __shfl_xor(s, 16, 64);  s  += __shfl_xor(s, 32, 64);
      s2 += __shfl_xor(s2, 16, 64); s2 += __shfl_xor(s2, 32, 64);
      if (quad == 0){
        atomicAdd(&p0[col], s);
        atomicAdd(&p1[col], s2);
      }
    }
  }
}

// ---------------- fp32 GEMM (MLP tail, small M) ----------------
template<bool RELU>
__global__ __launch_bounds__(256) void k_gemm(const float* __restrict__ A,
                                              const float* __restrict__ B,
                                              const float* __restrict__ bias,
                                              float* __restrict__ C,
                                              int M, int K, int Nc){
  __shared__ float As[16][68];
  __shared__ float Bs[16][64];
  const int tid = threadIdx.x;
  const int tx = tid & 15, ty = tid >> 4;
  const int bm = blockIdx.x * 64, bn = blockIdx.y * 64;
  const int arow = tid >> 2, akq = (tid & 3) << 2;
  const int brow = tid >> 4, bcol = (tid & 15) << 2;
  float acc[4][4] = {{0.f}};
  const bool aval = (bm + arow) < M;
  const float* Aptr = A + (size_t)(bm + arow) * K + akq;
  const float* Bptr = B + (size_t)brow * Nc + bn + bcol;
  for (int k0 = 0; k0 < K; k0 += 16){
    float4 av = make_float4(0.f, 0.f, 0.f, 0.f);
    if (aval) av = *(const float4*)(Aptr + k0);
    float4 bv = *(const float4*)(Bptr + (size_t)k0 * Nc);
    As[akq + 0][arow] = av.x;
    As[akq + 1][arow] = av.y;
    As[akq + 2][arow] = av.z;
    As[akq + 3][arow] = av.w;
    *(float4*)&Bs[brow][bcol] = bv;
    __syncthreads();
    #pragma unroll
    for (int kk = 0; kk < 16; kk++){
      const float4 a = *(const float4*)(&As[kk][ty << 2]);
      const float4 b = *(const float4*)(&Bs[kk][tx << 2]);
      const float ar[4] = {a.x, a.y, a.z, a.w};
      const float br[4] = {b.x, b.y, b.z, b.w};
      #pragma unroll
      for (int i = 0; i < 4; i++)
        #pragma unroll
        for (int j = 0; j < 4; j++)
          acc[i][j] = fmaf(ar[i], br[j], acc[i][j]);
    }
    __syncthreads();
  }
  const int col = bn + (tx << 2);
  const float4 bb = *(const float4*)(bias + col);
  #pragma unroll
  for (int i = 0; i < 4; i++){
    int row = bm + (ty << 2) + i;
    if (row < M){
      float4 o;
      o.x = acc[i][0] + bb.x;
      o.y = acc[i][1] + bb.y;
      o.z = acc[i][2] + bb.z;
      o.w = acc[i][3] + bb.w;
      if (RELU){
        o.x = fmaxf(o.x, 0.f); o.y = fmaxf(o.y, 0.f);
        o.z = fmaxf(o.z, 0.f); o.w = fmaxf(o.w, 0.f);
      }
      *(float4*)(C + (size_t)row * Nc + col) = o;
    }
  }
}

// ---------------- BatchNorm finalize ----------------

__global__ void k_bnfin(const float* __restrict__ sacc, const float* __restrict__ s2acc,
                        const float* __restrict__ g, const float* __restrict__ be,
                        float* __restrict__ scale, float* __restrict__ shift, int C){
  int c = blockIdx.x * blockDim.x + threadIdx.x;
  if (c >= C) return;
  float m = sacc[c] * (1.0f / NN);
  float v = s2acc[c] * (1.0f / NN) - m * m;
  float rs = rsqrtf(v + 1e-5f);
  float sc = g[c] * rs;
  scale[c] = sc;
  shift[c] = be[c] - m * sc;
}

// ---------------- mean pool: h2 bf16 [NN,1024] -> pooled fp32 [NG,1024] ----------------
// 2-way row split, 8 channels (16B) per thread, LDS combine
__global__ __launch_bounds__(256) void k_pool_b(const u16* __restrict__ h,
                                                const int* __restrict__ start,
                                                float* __restrict__ pooled){
  __shared__ float sm[128*8];
  int g = blockIdx.x;
  int half = threadIdx.x >> 7;
  int cb = threadIdx.x & 127;
  int c = cb << 3;
  int r0 = start[g], r1 = start[g + 1];
  float acc[8] = {0.f,0.f,0.f,0.f,0.f,0.f,0.f,0.f};
  for (int r = r0 + half; r < r1; r += 2){
    float b[8];
    up8(*(const uint4*)(h + (size_t)r * 1024 + c), b);
    #pragma unroll
    for (int k = 0; k < 8; k++) acc[k] += b[k];
  }
  if (half){
    #pragma unroll
    for (int k = 0; k < 8; k++) sm[cb*8 + k] = acc[k];
  }
  __syncthreads();
  if (!half){
    float inv = (r1 > r0) ? (1.0f / (float)(r1 - r0)) : 0.0f;
    float o[8];
    #pragma unroll
    for (int k = 0; k < 8; k++) o[k] = (acc[k] + sm[cb*8 + k]) * inv;
    float4* dst = (float4*)(pooled + (size_t)g * 1024 + c);
    dst[0] = make_float4(o[0], o[1], o[2], o[3]);
    dst[1] = make_float4(o[4], o[5], o[6], o[7]);
  }
}

// ---------------- host launcher ----------------

extern "C" void kernel_launch(void* const* d_in, const int* in_sizes, int n_in,
                              void* d_out, int out_size, void* d_ws, size_t ws_size,
                              hipStream_t stream) {
  const float* x    = (const float*)d_in[0];
  const int*   ei   = (const int*)d_in[1];
  const int*   bat  = (const int*)d_in[2];
  const float* w0   = (const float*)d_in[3];
  const float* b0   = (const float*)d_in[4];
  const float* a_w1 = (const float*)d_in[5],  *a_b1  = (const float*)d_in[6];
  const float* a_g1 = (const float*)d_in[7],  *a_be1 = (const float*)d_in[8];
  const float* a_w2 = (const float*)d_in[9],  *a_b2  = (const float*)d_in[10];
  const float* a_g2 = (const float*)d_in[11], *a_be2 = (const float*)d_in[12];
  const float* a_w3 = (const float*)d_in[13], *a_b3  = (const float*)d_in[14];
  const float* c_w1 = (const float*)d_in[15], *c_b1  = (const float*)d_in[16];
  const float* c_g1 = (const float*)d_in[17], *c_be1 = (const float*)d_in[18];
  const float* c_w2 = (const float*)d_in[19], *c_b2  = (const float*)d_in[20];
  const float* c_g2 = (const float*)d_in[21], *c_be2 = (const float*)d_in[22];
  const float* c_w3 = (const float*)d_in[23], *c_b3  = (const float*)d_in[24];
  const float* mw1  = (const float*)d_in[25], *mb1   = (const float*)d_in[26];
  const float* mw2  = (const float*)d_in[27], *mb2   = (const float*)d_in[28];
  float* out = (float*)d_out;

  char* pp = (char*)d_ws;
  auto alloc = [&](size_t b)->char*{ char* r = pp; pp += (b + 255) & ~(size_t)255; return r; };

  const size_t CH = (size_t)NN * 2;
  char* R = alloc(2304 * CH);                      // 92.16 MB
  float* dinv = (float*)alloc((size_t)NN * 4);
  int* icomb  = (int*)alloc((size_t)2 * NN * 4);   // deg + cur (contiguous, one zero)
  int* deg    = icomb;
  int* cur    = icomb + NN;
  int* offs   = (int*)alloc((size_t)(NN + 1) * 4);
  int* bsum   = (int*)alloc((size_t)(NB + 1) * 4);
  int* srcs   = (int*)alloc((size_t)NE * 4);
  int* startg = (int*)alloc((size_t)(NG + 1) * 4);
  // per-layer BN stat buffers (sum at +0, sumsq at +C), zeroed once upfront
  float* SB   = (float*)alloc(5376 * 4);
  float* sA1 = SB;          // 384*2
  float* sA2 = SB + 768;    // 512*2
  float* sC1 = SB + 1792;   // 768*2
  float* sC2 = SB + 3328;   // 1024*2
  float* scv  = (float*)alloc(1024 * 4);
  float* shv  = (float*)alloc(1024 * 4);
  u16* WT  = (u16*)alloc(2162688 * 2);             // 4.33 MB
  u16* wt0  = WT;                // 256x128
  u16* wtA1 = WT + 32768;        // 384x256
  u16* wtA2 = WT + 131072;       // 512x384
  u16* wtA3 = WT + 327680;       // 512x256
  u16* wtC1 = WT + 458752;       // 768x512
  u16* wtC2 = WT + 851968;       // 1024x768
  u16* wtC3 = WT + 1638400;      // 1024x512
  float* P  = (float*)WT;        // overlaid with WT (disjoint lifetime)
  float* Hh = P + (size_t)NG * 1024;

  auto slot = [&](int s)->u16*{ return (u16*)(R + (size_t)s * CH); };
  u16* xb  = slot(512);
  u16* ax  = slot(0);
  u16* h0  = slot(128);
  u16* ah0 = slot(1664);
  u16* t1  = slot(1920);
  u16* at  = slot(1280);
  u16* h1  = slot(768);
  u16* ah1 = slot(1792);
  u16* u1  = slot(0);
  u16* au  = slot(1024);
  u16* h2  = slot(0);

  auto cdiv = [](int a, int b){ return (a + b - 1) / b; };

  // graph preprocessing
  k_zero<<<cdiv(2*NN,256),256,0,stream>>>(icomb, 2*NN);
  k_zero<<<cdiv(5376,256),256,0,stream>>>((int*)SB, 5376);
  k_deg <<<cdiv(NE,256),256,0,stream>>>(ei, deg);
  k_dinv<<<cdiv(NN,256),256,0,stream>>>(deg, dinv);
  k_scan1<<<NB,256,0,stream>>>(deg, bsum);
  k_scan2<<<1,64,0,stream>>>(bsum);
  k_scan3<<<NB,256,0,stream>>>(deg, bsum, offs);
  k_fill<<<cdiv(NE,256),256,0,stream>>>(ei, offs, cur, srcs);
  k_bounds<<<cdiv(NN,256),256,0,stream>>>(bat, startg);
  k_cast<<<cdiv(NN*32,256),256,0,stream>>>((const float4*)x, (ushort4*)xb, NN*32);

  // weight prep (fp32 [K,N] -> bf16 [N,K])
  k_wprep<<<dim3(2,4),  256,0,stream>>>(w0,   wt0,  128, 256);
  k_wprep<<<dim3(4,6),  256,0,stream>>>(a_w1, wtA1, 256, 384);
  k_wprep<<<dim3(6,8),  256,0,stream>>>(a_w2, wtA2, 384, 512);
  k_wprep<<<dim3(4,8),  256,0,stream>>>(a_w3, wtA3, 256, 512);
  k_wprep<<<dim3(8,12), 256,0,stream>>>(c_w1, wtC1, 512, 768);
  k_wprep<<<dim3(12,16),256,0,stream>>>(c_w2, wtC2, 768, 1024);
  k_wprep<<<dim3(8,16), 256,0,stream>>>(c_w3, wtC3, 512, 1024);

  auto agg = [&](const u16* in, u16* o, int C, bool bnf){
    int C8 = C / 8;
    int gb = cdiv(NN * C8, 256);
    if (!bnf){
      switch (C8){
        case 16: k_agg_b<16,false><<<gb,256,0,stream>>>((const uint4*)in,(uint4*)o,dinv,offs,srcs,nullptr,nullptr); break;
        case 32: k_agg_b<32,false><<<gb,256,0,stream>>>((const uint4*)in,(uint4*)o,dinv,offs,srcs,nullptr,nullptr); break;
        case 64: k_agg_b<64,false><<<gb,256,0,stream>>>((const uint4*)in,(uint4*)o,dinv,offs,srcs,nullptr,nullptr); break;
        default: break;
      }
    } else {
      switch (C8){
        case 48: k_agg_b<48,true><<<gb,256,0,stream>>>((const uint4*)in,(uint4*)o,dinv,offs,srcs,scv,shv); break;
        case 96: k_agg_b<96,true><<<gb,256,0,stream>>>((const uint4*)in,(uint4*)o,dinv,offs,srcs,scv,shv); break;
        default: break;
      }
    }
  };
  // mode: 0=bias, 1=bias+relu, 2=bias+add, 3=bias + relu(sc*C_old+sh) add
  auto gemm_m = [&](const u16* A, const u16* BT_, const float* bi, u16* Cc,
                    int K, int Nc, int mode, float* sbuf, int sC){
    dim3 g(cdiv(NN,128), Nc/128);
    if (sbuf){
      k_mfma<0,true><<<g,256,0,stream>>>(A, BT_, bi, Cc, sbuf, sbuf + sC, NN, K, Nc);
    } else if (mode == 0)
      k_mfma<0,false><<<g,256,0,stream>>>(A, BT_, bi, Cc, nullptr, nullptr, NN, K, Nc);
    else if (mode == 1)
      k_mfma<1,false><<<g,256,0,stream>>>(A, BT_, bi, Cc, nullptr, nullptr, NN, K, Nc);
    else if (mode == 2)
      k_mfma<2,false><<<g,256,0,stream>>>(A, BT_, bi, Cc, nullptr, nullptr, NN, K, Nc);
    else
      k_mfma<3,false><<<g,256,0,stream>>>(A, BT_, bi, Cc, scv, shv, NN, K, Nc);
  };
  auto bnfin = [&](const float* sbuf, const float* g, const float* be, int C){
    k_bnfin<<<cdiv(C,256),256,0,stream>>>(sbuf, sbuf + C, g, be, scv, shv, C);
  };

  // stem
  agg(xb, ax, 128, false);
  gemm_m(ax, wt0, b0, h0, 128, 256, 1, nullptr, 0);
  // block0 (256 -> 384 -> 512)
  agg(h0, ah0, 256, false);
  gemm_m(ah0, wtA1, a_b1, t1, 256, 384, 0, sA1, 384);   // t1raw + stats
  bnfin(sA1, a_g1, a_be1, 384);
  agg(t1, at, 384, true);                               // at = agg(relu(bn(t1raw)))
  gemm_m(at, wtA2, a_b2, h1, 384, 512, 0, sA2, 512);    // t2raw + stats
  bnfin(sA2, a_g2, a_be2, 512);
  gemm_m(ah0, wtA3, a_b3, h1, 256, 512, 3, nullptr, 0); // h1 = relu(bn(t2raw)) + ah0@w3+b3
  // block1 (512 -> 768 -> 1024)
  agg(h1, ah1, 512, false);
  gemm_m(ah1, wtC1, c_b1, u1, 512, 768, 0, sC1, 768);   // u1raw + stats
  bnfin(sC1, c_g1, c_be1, 768);
  agg(u1, au, 768, true);                               // au = agg(relu(bn(u1raw)))
  gemm_m(au, wtC2, c_b2, h2, 768, 1024, 0, sC2, 1024);  // u2raw + stats
  bnfin(sC2, c_g2, c_be2, 1024);
  gemm_m(ah1, wtC3, c_b3, h2, 512, 1024, 3, nullptr, 0);// h2 = relu(bn(u2raw)) + ah1@c_w3+c_b3
  // pool + MLP (fp32)
  k_pool_b<<<NG,256,0,stream>>>(h2, startg, P);
  {
    dim3 g1(cdiv(NG,64), 1024/64);
    k_gemm<true><<<g1,256,0,stream>>>(P, mw1, mb1, Hh, NG, 1024, 1024);
    dim3 g2(cdiv(NG,64), 768/64);
    k_gemm<false><<<g2,256,0,stream>>>(Hh, mw2, mb2, out, NG, 1024, 768);
  }
}

// Round 8
// 731.204 us; speedup vs baseline: 2.8117x; 1.0864x over previous
//
#include <hip/hip_runtime.h>
#include <cstdint>
#include <cstddef>

#define NN 20000
#define NE 320000
#define NG 256
#define NB 79   // ceil(NN/256)

typedef unsigned short u16;
typedef __attribute__((ext_vector_type(8))) short bf16x8;
typedef __attribute__((ext_vector_type(4))) float f32x4;

// ---------------- bf16 helpers (storage bf16, math fp32) ----------------
__device__ inline float b2f(u16 h){
  union { unsigned u; float f; } v; v.u = ((unsigned)h) << 16; return v.f;
}
__device__ inline u16 f2b(float f){
  union { float f; unsigned u; } v; v.f = f;
  unsigned r = v.u + 0x7FFFu + ((v.u >> 16) & 1u);   // round-nearest-even
  return (u16)(r >> 16);
}
__device__ inline void up8(const uint4& v, float* a){
  union { unsigned u; float f; } t;
  t.u = v.x << 16;         a[0] = t.f;
  t.u = v.x & 0xffff0000u; a[1] = t.f;
  t.u = v.y << 16;         a[2] = t.f;
  t.u = v.y & 0xffff0000u; a[3] = t.f;
  t.u = v.z << 16;         a[4] = t.f;
  t.u = v.z & 0xffff0000u; a[5] = t.f;
  t.u = v.w << 16;         a[6] = t.f;
  t.u = v.w & 0xffff0000u; a[7] = t.f;
}
__device__ inline unsigned pk2(float a, float b){
  return (unsigned)f2b(a) | (((unsigned)f2b(b)) << 16);
}
__device__ inline void bnrelu8(float* b, const float* sc, const float* sh){
  #pragma unroll
  for (int k = 0; k < 8; k++) b[k] = fmaxf(fmaf(b[k], sc[k], sh[k]), 0.f);
}

__device__ inline void gload_lds16(const void* g, void* l){
  __builtin_amdgcn_global_load_lds(
      (const __attribute__((address_space(1))) unsigned int*)g,
      (__attribute__((address_space(3))) unsigned int*)l, 16, 0, 0);
}

// ---------------- utility kernels ----------------

__global__ void k_zero(int* __restrict__ p, int n){
  int i = blockIdx.x*blockDim.x + threadIdx.x;
  if (i < n) p[i] = 0;
}

__global__ void k_deg(const int* __restrict__ ei, int* __restrict__ deg){
  int e = blockIdx.x*blockDim.x + threadIdx.x;
  if (e < NE) atomicAdd(&deg[ei[NE + e]], 1);   // dst = ei[1][e]
}

// two-level scan: counts[NN] -> offs[NN+1]; also emits dinv
__global__ void k_scan1(const int* __restrict__ counts, int* __restrict__ bsum,
                        float* __restrict__ dinv){
  __shared__ int sm[256];
  int b = blockIdx.x, tid = threadIdx.x, idx = b*256 + tid;
  int v = (idx < NN) ? counts[idx] : 0;
  if (idx < NN) dinv[idx] = rsqrtf(1.0f + (float)v);
  sm[tid] = v;
  __syncthreads();
  for (int d = 128; d > 0; d >>= 1){
    if (tid < d) sm[tid] += sm[tid + d];
    __syncthreads();
  }
  if (tid == 0) bsum[b] = sm[0];
}
__global__ void k_scan2(int* __restrict__ bsum){
  if (threadIdx.x == 0){
    int c = 0;
    for (int i = 0; i < NB; i++){ int t = bsum[i]; bsum[i] = c; c += t; }
    bsum[NB] = c;
  }
}
__global__ void k_scan3(const int* __restrict__ counts, const int* __restrict__ bsum,
                        int* __restrict__ offs){
  __shared__ int sm[256];
  int b = blockIdx.x, tid = threadIdx.x, idx = b*256 + tid;
  int v = (idx < NN) ? counts[idx] : 0;
  sm[tid] = v;
  __syncthreads();
  for (int d = 1; d < 256; d <<= 1){
    int t = (tid >= d) ? sm[tid - d] : 0;
    __syncthreads();
    sm[tid] += t;
    __syncthreads();
  }
  if (idx < NN) offs[idx] = bsum[b] + sm[tid] - v;
  if (idx == NN - 1) offs[NN] = bsum[NB];
}

__global__ void k_fill(const int* __restrict__ ei, const int* __restrict__ offs,
                       int* __restrict__ cur, int* __restrict__ srcs){
  int e = blockIdx.x*blockDim.x + threadIdx.x;
  if (e < NE){
    int s = ei[e];
    int d = ei[NE + e];
    int p = atomicAdd(&cur[d], 1);
    srcs[offs[d] + p] = s;
  }
}

__global__ void k_bounds(const int* __restrict__ batch, int* __restrict__ start){
  int i = blockIdx.x*blockDim.x + threadIdx.x;
  if (i < NN){
    int b  = batch[i];
    int bp = (i == 0) ? -1 : batch[i-1];
    for (int g = bp + 1; g <= b; g++) start[g] = i;
    if (i == NN - 1){
      for (int g = b + 1; g <= NG; g++) start[g] = NN;
    }
  }
}

__global__ void k_cast(const float4* __restrict__ x, ushort4* __restrict__ xb, int total4){
  int t = blockIdx.x*blockDim.x + threadIdx.x;
  if (t >= total4) return;
  float4 v = x[t];
  ushort4 o; o.x = f2b(v.x); o.y = f2b(v.y); o.z = f2b(v.z); o.w = f2b(v.w);
  xb[t] = o;
}

// weight prep: fp32 [K,N] row-major -> bf16 [N,K] row-major (tiled transpose)
__global__ __launch_bounds__(256) void k_wprep(const float* __restrict__ w,
                                               u16* __restrict__ wt, int K, int N){
  __shared__ float sm[64][65];
  int kb = blockIdx.x * 64, nb = blockIdx.y * 64;
  int tid = threadIdx.x;
  #pragma unroll
  for (int i = 0; i < 16; i++){
    int t = i*256 + tid;
    int r = t >> 6, c = t & 63;
    sm[r][c] = w[(size_t)(kb + r) * N + nb + c];
  }
  __syncthreads();
  #pragma unroll
  for (int i = 0; i < 16; i++){
    int t = i*256 + tid;
    int r = t >> 6, c = t & 63;
    wt[(size_t)(nb + r) * K + kb + c] = f2b(sm[c][r]);
  }
}

// ---------------- aggregation (bf16 in/out, fp32 accumulate) ----------------
// T(x) = BN ? relu(sc*x+sh) : x with sc/sh derived inline from raw stats.
template<int C8, bool BN>
__global__ void k_agg_b(const uint4* __restrict__ in, uint4* __restrict__ out,
                        const float* __restrict__ dinv, const int* __restrict__ offs,
                        const int* __restrict__ srcs,
                        const float* __restrict__ sumv, const float* __restrict__ sqv,
                        const float* __restrict__ gam,  const float* __restrict__ bet){
  int t = blockIdx.x*blockDim.x + threadIdx.x;
  if (t >= NN * C8) return;
  int i = t / C8;
  int c = t - i * C8;
  float sc[8], sh[8];
  if (BN){
    #pragma unroll
    for (int k = 0; k < 8; k++){
      int ch = c*8 + k;
      float m  = sumv[ch] * (1.0f / NN);
      float vv = sqv[ch] * (1.0f / NN) - m * m;
      float rs = rsqrtf(vv + 1e-5f);
      sc[k] = gam[ch] * rs;
      sh[k] = bet[ch] - m * sc[k];
    }
  }
  float di = dinv[i];
  float a[8], acc[8];
  up8(in[t], a);
  if (BN) bnrelu8(a, sc, sh);
  #pragma unroll
  for (int k = 0; k < 8; k++) acc[k] = a[k] * di;

  int e = offs[i], e1 = offs[i + 1];
  for (; e + 4 <= e1; e += 4){
    int sA = srcs[e], sB = srcs[e+1], sC = srcs[e+2], sD = srcs[e+3];
    float dA = dinv[sA], dB = dinv[sB], dC = dinv[sC], dD = dinv[sD];
    uint4 yA = in[(size_t)sA * C8 + c];
    uint4 yB = in[(size_t)sB * C8 + c];
    uint4 yC = in[(size_t)sC * C8 + c];
    uint4 yD = in[(size_t)sD * C8 + c];
    float b[8];
    up8(yA, b);
    if (BN) bnrelu8(b, sc, sh);
    #pragma unroll
    for (int k = 0; k < 8; k++) acc[k] = fmaf(b[k], dA, acc[k]);
    up8(yB, b);
    if (BN) bnrelu8(b, sc, sh);
    #pragma unroll
    for (int k = 0; k < 8; k++) acc[k] = fmaf(b[k], dB, acc[k]);
    up8(yC, b);
    if (BN) bnrelu8(b, sc, sh);
    #pragma unroll
    for (int k = 0; k < 8; k++) acc[k] = fmaf(b[k], dC, acc[k]);
    up8(yD, b);
    if (BN) bnrelu8(b, sc, sh);
    #pragma unroll
    for (int k = 0; k < 8; k++) acc[k] = fmaf(b[k], dD, acc[k]);
  }
  for (; e < e1; e++){
    int s = srcs[e];
    float ds = dinv[s];
    float b[8];
    up8(in[(size_t)s * C8 + c], b);
    if (BN) bnrelu8(b, sc, sh);
    #pragma unroll
    for (int k = 0; k < 8; k++) acc[k] = fmaf(b[k], ds, acc[k]);
  }
  #pragma unroll
  for (int k = 0; k < 8; k++) acc[k] *= di;
  uint4 o;
  o.x = pk2(acc[0], acc[1]); o.y = pk2(acc[2], acc[3]);
  o.z = pk2(acc[4], acc[5]); o.w = pk2(acc[6], acc[7]);
  out[t] = o;
}

// ---------------- MFMA GEMM: A bf16 [M,K], BT bf16 [N,K], C bf16 [M,N] ----------------
// 128x128 tile, BK=64, 256 threads (4 waves, 2x2), 4x4 16x16x32 frags/wave.
// Epilogue: results rounded to bf16 into LDS (reusing staging space), then
// blasted to global as uint4 (16B/lane) — avoids partial-line write amplification.
// MODE: 0=bias, 1=bias+relu, 3=bias + relu(BN(C_old)) add (BN from raw stats p0..p3)
// STATS: accumulate per-column sum/sumsq of (acc+bias) into p0/p1
template<int MODE, bool STATS>
__global__ __launch_bounds__(256, 4) void k_mfma(const u16* __restrict__ A,
                                                 const u16* __restrict__ BT,
                                                 const float* __restrict__ bias,
                                                 u16* __restrict__ C,
                                                 float* __restrict__ p0,
                                                 float* __restrict__ p1,
                                                 const float* __restrict__ p2,
                                                 const float* __restrict__ p3,
                                                 int M, int K, int Nc){
  __shared__ u16 S[128*128];          // staging: As = S[0:8192), Bs = S[8192:16384)
  u16* As = S;
  u16* Bs = S + 128*64;
  const int tid = threadIdx.x;
  const int lane = tid & 63;
  const int quad = lane >> 4;
  const int l16 = lane & 15;
  const int wid = tid >> 6;
  const int wm = wid & 1, wn = wid >> 1;
  const int bm = blockIdx.x * 128, bn = blockIdx.y * 128;

  f32x4 acc[4][4];
  #pragma unroll
  for (int i = 0; i < 4; i++)
    #pragma unroll
    for (int j = 0; j < 4; j++)
      acc[i][j] = (f32x4){0.f, 0.f, 0.f, 0.f};

  const int srow = tid >> 3;
  const int scol8 = tid & 7;
  for (int k0 = 0; k0 < K; k0 += 64){
    #pragma unroll
    for (int i = 0; i < 4; i++){
      int row = i*32 + srow;
      int gc = (scol8 ^ (row & 7)) * 8;
      int lofs = row*64 + scol8*8;
      gload_lds16(A + (size_t)(bm + row) * K + k0 + gc, As + lofs);
      gload_lds16(BT + (size_t)(bn + row) * K + k0 + gc, Bs + lofs);
    }
    __syncthreads();
    #pragma unroll
    for (int kk = 0; kk < 2; kk++){
      const int col8 = kk*4 + quad;
      bf16x8 af[4], bfr[4];
      #pragma unroll
      for (int mi = 0; mi < 4; mi++){
        int row = wm*64 + mi*16 + l16;
        af[mi] = *(const bf16x8*)(As + row*64 + ((col8 ^ (row & 7)) * 8));
      }
      #pragma unroll
      for (int ni = 0; ni < 4; ni++){
        int row = wn*64 + ni*16 + l16;
        bfr[ni] = *(const bf16x8*)(Bs + row*64 + ((col8 ^ (row & 7)) * 8));
      }
      #pragma unroll
      for (int mi = 0; mi < 4; mi++)
        #pragma unroll
        for (int ni = 0; ni < 4; ni++)
          acc[mi][ni] = __builtin_amdgcn_mfma_f32_16x16x32_bf16(af[mi], bfr[ni], acc[mi][ni], 0, 0, 0);
    }
    __syncthreads();
  }
  // register epilogue: bias (+stats, +relu), round to bf16 into LDS [row][col]
  #pragma unroll
  for (int ni = 0; ni < 4; ni++){
    int colL = wn*64 + ni*16 + l16;
    float bb = bias[bn + colL];
    float s = 0.f, s2 = 0.f;
    #pragma unroll
    for (int mi = 0; mi < 4; mi++){
      int rbase = wm*64 + mi*16 + quad*4;
      #pragma unroll
      for (int r = 0; r < 4; r++){
        int rowL = rbase + r;
        float v = acc[mi][ni][r] + bb;
        if (STATS && (bm + rowL) < M){ s += v; s2 += v * v; }
        if (MODE == 1) v = fmaxf(v, 0.f);
        S[rowL*128 + colL] = f2b(v);
      }
    }
    if (STATS){
      s  += __shfl_xor(s, 16, 64);  s  += __shfl_xor(s, 32, 64);
      s2 += __shfl_xor(s2, 16, 64); s2 += __shfl_xor(s2, 32, 64);
      if (quad == 0){
        atomicAdd(&p0[bn + colL], s);
        atomicAdd(&p1[bn + colL], s2);
      }
    }
  }
  __syncthreads();
  // blast: 16B per lane, full-line coalesced stores
  #pragma unroll
  for (int it = 0; it < 8; it++){
    int idx = it*256 + tid;
    int rl = idx >> 4, cq = idx & 15;
    int row = bm + rl;
    if (row < M){
      int col0 = bn + cq*8;
      uint4 w = *(const uint4*)(S + rl*128 + cq*8);
      u16* cp = C + (size_t)row * Nc + col0;
      if (MODE == 3){
        float o[8], ov[8];
        up8(w, o);
        uint4 old = *(const uint4*)cp;
        up8(old, ov);
        #pragma unroll
        for (int k = 0; k < 8; k++){
          int ch = col0 + k;
          float m  = p0[ch] * (1.0f / NN);
          float vv = p1[ch] * (1.0f / NN) - m * m;
          float rs = rsqrtf(vv + 1e-5f);
          float sc = p2[ch] * rs;
          float sh = p3[ch] - m * sc;
          o[k] += fmaxf(fmaf(ov[k], sc, sh), 0.f);
        }
        uint4 ou;
        ou.x = pk2(o[0], o[1]); ou.y = pk2(o[2], o[3]);
        ou.z = pk2(o[4], o[5]); ou.w = pk2(o[6], o[7]);
        *(uint4*)cp = ou;
      } else {
        *(uint4*)cp = w;
      }
    }
  }
}

// ---------------- fp32 GEMM (MLP tail, small M) ----------------
template<bool RELU>
__global__ __launch_bounds__(256) void k_gemm(const float* __restrict__ A,
                                              const float* __restrict__ B,
                                              const float* __restrict__ bias,
                                              float* __restrict__ C,
                                              int M, int K, int Nc){
  __shared__ float As[16][68];
  __shared__ float Bs[16][64];
  const int tid = threadIdx.x;
  const int tx = tid & 15, ty = tid >> 4;
  const int bm = blockIdx.x * 64, bn = blockIdx.y * 64;
  const int arow = tid >> 2, akq = (tid & 3) << 2;
  const int brow = tid >> 4, bcol = (tid & 15) << 2;
  float acc[4][4] = {{0.f}};
  const bool aval = (bm + arow) < M;
  const float* Aptr = A + (size_t)(bm + arow) * K + akq;
  const float* Bptr = B + (size_t)brow * Nc + bn + bcol;
  for (int k0 = 0; k0 < K; k0 += 16){
    float4 av = make_float4(0.f, 0.f, 0.f, 0.f);
    if (aval) av = *(const float4*)(Aptr + k0);
    float4 bv = *(const float4*)(Bptr + (size_t)k0 * Nc);
    As[akq + 0][arow] = av.x;
    As[akq + 1][arow] = av.y;
    As[akq + 2][arow] = av.z;
    As[akq + 3][arow] = av.w;
    *(float4*)&Bs[brow][bcol] = bv;
    __syncthreads();
    #pragma unroll
    for (int kk = 0; kk < 16; kk++){
      const float4 a = *(const float4*)(&As[kk][ty << 2]);
      const float4 b = *(const float4*)(&Bs[kk][tx << 2]);
      const float ar[4] = {a.x, a.y, a.z, a.w};
      const float br[4] = {b.x, b.y, b.z, b.w};
      #pragma unroll
      for (int i = 0; i < 4; i++)
        #pragma unroll
        for (int j = 0; j < 4; j++)
          acc[i][j] = fmaf(ar[i], br[j], acc[i][j]);
    }
    __syncthreads();
  }
  const int col = bn + (tx << 2);
  const float4 bb = *(const float4*)(bias + col);
  #pragma unroll
  for (int i = 0; i < 4; i++){
    int row = bm + (ty << 2) + i;
    if (row < M){
      float4 o;
      o.x = acc[i][0] + bb.x;
      o.y = acc[i][1] + bb.y;
      o.z = acc[i][2] + bb.z;
      o.w = acc[i][3] + bb.w;
      if (RELU){
        o.x = fmaxf(o.x, 0.f); o.y = fmaxf(o.y, 0.f);
        o.z = fmaxf(o.z, 0.f); o.w = fmaxf(o.w, 0.f);
      }
      *(float4*)(C + (size_t)row * Nc + col) = o;
    }
  }
}

// ---------------- mean pool: h2 bf16 [NN,1024] -> pooled fp32 [NG,1024] ----------------
__global__ __launch_bounds__(256) void k_pool_b(const u16* __restrict__ h,
                                                const int* __restrict__ start,
                                                float* __restrict__ pooled){
  __shared__ float sm[128*8];
  int g = blockIdx.x;
  int half = threadIdx.x >> 7;
  int cb = threadIdx.x & 127;
  int c = cb << 3;
  int r0 = start[g], r1 = start[g + 1];
  float acc[8] = {0.f,0.f,0.f,0.f,0.f,0.f,0.f,0.f};
  for (int r = r0 + half; r < r1; r += 2){
    float b[8];
    up8(*(const uint4*)(h + (size_t)r * 1024 + c), b);
    #pragma unroll
    for (int k = 0; k < 8; k++) acc[k] += b[k];
  }
  if (half){
    #pragma unroll
    for (int k = 0; k < 8; k++) sm[cb*8 + k] = acc[k];
  }
  __syncthreads();
  if (!half){
    float inv = (r1 > r0) ? (1.0f / (float)(r1 - r0)) : 0.0f;
    float o[8];
    #pragma unroll
    for (int k = 0; k < 8; k++) o[k] = (acc[k] + sm[cb*8 + k]) * inv;
    float4* dst = (float4*)(pooled + (size_t)g * 1024 + c);
    dst[0] = make_float4(o[0], o[1], o[2], o[3]);
    dst[1] = make_float4(o[4], o[5], o[6], o[7]);
  }
}

// ---------------- host launcher ----------------

extern "C" void kernel_launch(void* const* d_in, const int* in_sizes, int n_in,
                              void* d_out, int out_size, void* d_ws, size_t ws_size,
                              hipStream_t stream) {
  const float* x    = (const float*)d_in[0];
  const int*   ei   = (const int*)d_in[1];
  const int*   bat  = (const int*)d_in[2];
  const float* w0   = (const float*)d_in[3];
  const float* b0   = (const float*)d_in[4];
  const float* a_w1 = (const float*)d_in[5],  *a_b1  = (const float*)d_in[6];
  const float* a_g1 = (const float*)d_in[7],  *a_be1 = (const float*)d_in[8];
  const float* a_w2 = (const float*)d_in[9],  *a_b2  = (const float*)d_in[10];
  const float* a_g2 = (const float*)d_in[11], *a_be2 = (const float*)d_in[12];
  const float* a_w3 = (const float*)d_in[13], *a_b3  = (const float*)d_in[14];
  const float* c_w1 = (const float*)d_in[15], *c_b1  = (const float*)d_in[16];
  const float* c_g1 = (const float*)d_in[17], *c_be1 = (const float*)d_in[18];
  const float* c_w2 = (const float*)d_in[19], *c_b2  = (const float*)d_in[20];
  const float* c_g2 = (const float*)d_in[21], *c_be2 = (const float*)d_in[22];
  const float* c_w3 = (const float*)d_in[23], *c_b3  = (const float*)d_in[24];
  const float* mw1  = (const float*)d_in[25], *mb1   = (const float*)d_in[26];
  const float* mw2  = (const float*)d_in[27], *mb2   = (const float*)d_in[28];
  float* out = (float*)d_out;

  char* pp = (char*)d_ws;
  auto alloc = [&](size_t b)->char*{ char* r = pp; pp += (b + 255) & ~(size_t)255; return r; };

  const size_t CH = (size_t)NN * 2;
  char* R = alloc(2304 * CH);                      // 92.16 MB
  float* dinv = (float*)alloc((size_t)NN * 4);
  int* icomb  = (int*)alloc((size_t)2 * NN * 4);   // deg + cur
  int* deg    = icomb;
  int* cur    = icomb + NN;
  int* offs   = (int*)alloc((size_t)(NN + 1) * 4);
  int* bsum   = (int*)alloc((size_t)(NB + 1) * 4);
  int* srcs   = (int*)alloc((size_t)NE * 4);
  int* startg = (int*)alloc((size_t)(NG + 1) * 4);
  // per-layer BN stat buffers (sum at +0, sumsq at +C), zeroed once upfront
  float* SB   = (float*)alloc(5376 * 4);
  float* sA1 = SB;          // 384*2
  float* sA2 = SB + 768;    // 512*2
  float* sC1 = SB + 1792;   // 768*2
  float* sC2 = SB + 3328;   // 1024*2
  u16* WT  = (u16*)alloc(2162688 * 2);             // 4.33 MB
  u16* wt0  = WT;                // 256x128
  u16* wtA1 = WT + 32768;        // 384x256
  u16* wtA2 = WT + 131072;       // 512x384
  u16* wtA3 = WT + 327680;       // 512x256
  u16* wtC1 = WT + 458752;       // 768x512
  u16* wtC2 = WT + 851968;       // 1024x768
  u16* wtC3 = WT + 1638400;      // 1024x512
  float* P  = (float*)WT;        // overlaid with WT (disjoint lifetime)
  float* Hh = P + (size_t)NG * 1024;

  auto slot = [&](int s)->u16*{ return (u16*)(R + (size_t)s * CH); };
  u16* xb  = slot(512);
  u16* ax  = slot(0);
  u16* h0  = slot(128);
  u16* ah0 = slot(1664);
  u16* t1  = slot(1920);
  u16* at  = slot(1280);
  u16* h1  = slot(768);
  u16* ah1 = slot(1792);
  u16* u1  = slot(0);
  u16* au  = slot(1024);
  u16* h2  = slot(0);

  auto cdiv = [](int a, int b){ return (a + b - 1) / b; };

  // graph preprocessing
  k_zero<<<cdiv(2*NN,256),256,0,stream>>>(icomb, 2*NN);
  k_zero<<<cdiv(5376,256),256,0,stream>>>((int*)SB, 5376);
  k_deg <<<cdiv(NE,256),256,0,stream>>>(ei, deg);
  k_scan1<<<NB,256,0,stream>>>(deg, bsum, dinv);
  k_scan2<<<1,64,0,stream>>>(bsum);
  k_scan3<<<NB,256,0,stream>>>(deg, bsum, offs);
  k_fill<<<cdiv(NE,256),256,0,stream>>>(ei, offs, cur, srcs);
  k_bounds<<<cdiv(NN,256),256,0,stream>>>(bat, startg);
  k_cast<<<cdiv(NN*32,256),256,0,stream>>>((const float4*)x, (ushort4*)xb, NN*32);

  // weight prep (fp32 [K,N] -> bf16 [N,K])
  k_wprep<<<dim3(2,4),  256,0,stream>>>(w0,   wt0,  128, 256);
  k_wprep<<<dim3(4,6),  256,0,stream>>>(a_w1, wtA1, 256, 384);
  k_wprep<<<dim3(6,8),  256,0,stream>>>(a_w2, wtA2, 384, 512);
  k_wprep<<<dim3(4,8),  256,0,stream>>>(a_w3, wtA3, 256, 512);
  k_wprep<<<dim3(8,12), 256,0,stream>>>(c_w1, wtC1, 512, 768);
  k_wprep<<<dim3(12,16),256,0,stream>>>(c_w2, wtC2, 768, 1024);
  k_wprep<<<dim3(8,16), 256,0,stream>>>(c_w3, wtC3, 512, 1024);

  // agg: plain, or fused BN-apply of input from raw stats
  auto agg = [&](const u16* in, u16* o, int C, const float* st,
                 const float* g, const float* be){
    int C8 = C / 8;
    int gb = cdiv(NN * C8, 256);
    if (!st){
      switch (C8){
        case 16: k_agg_b<16,false><<<gb,256,0,stream>>>((const uint4*)in,(uint4*)o,dinv,offs,srcs,nullptr,nullptr,nullptr,nullptr); break;
        case 32: k_agg_b<32,false><<<gb,256,0,stream>>>((const uint4*)in,(uint4*)o,dinv,offs,srcs,nullptr,nullptr,nullptr,nullptr); break;
        case 64: k_agg_b<64,false><<<gb,256,0,stream>>>((const uint4*)in,(uint4*)o,dinv,offs,srcs,nullptr,nullptr,nullptr,nullptr); break;
        default: break;
      }
    } else {
      switch (C8){
        case 48: k_agg_b<48,true><<<gb,256,0,stream>>>((const uint4*)in,(uint4*)o,dinv,offs,srcs,st,st+C,g,be); break;
        case 96: k_agg_b<96,true><<<gb,256,0,stream>>>((const uint4*)in,(uint4*)o,dinv,offs,srcs,st,st+C,g,be); break;
        default: break;
      }
    }
  };
  // mode 0+stats, mode 1 (relu), mode 3 (BN(old C) + add; st/g2/b2 = stats & params of that BN)
  auto gemm_m = [&](const u16* A, const u16* BT_, const float* bi, u16* Cc,
                    int K, int Nc, int mode, float* st, int sC,
                    const float* g2, const float* b2){
    dim3 g(cdiv(NN,128), Nc/128);
    if (mode == 0)
      k_mfma<0,true><<<g,256,0,stream>>>(A, BT_, bi, Cc, st, st + sC, nullptr, nullptr, NN, K, Nc);
    else if (mode == 1)
      k_mfma<1,false><<<g,256,0,stream>>>(A, BT_, bi, Cc, nullptr, nullptr, nullptr, nullptr, NN, K, Nc);
    else
      k_mfma<3,false><<<g,256,0,stream>>>(A, BT_, bi, Cc, st, st + sC, g2, b2, NN, K, Nc);
  };

  // stem
  agg(xb, ax, 128, nullptr, nullptr, nullptr);
  gemm_m(ax, wt0, b0, h0, 128, 256, 1, nullptr, 0, nullptr, nullptr);
  // block0 (256 -> 384 -> 512)
  agg(h0, ah0, 256, nullptr, nullptr, nullptr);
  gemm_m(ah0, wtA1, a_b1, t1, 256, 384, 0, sA1, 384, nullptr, nullptr);  // t1raw + stats
  agg(t1, at, 384, sA1, a_g1, a_be1);                                    // at = agg(relu(bn(t1raw)))
  gemm_m(at, wtA2, a_b2, h1, 384, 512, 0, sA2, 512, nullptr, nullptr);   // t2raw + stats
  gemm_m(ah0, wtA3, a_b3, h1, 256, 512, 3, sA2, 512, a_g2, a_be2);       // h1 = relu(bn(t2raw)) + ah0@w3+b3
  // block1 (512 -> 768 -> 1024)
  agg(h1, ah1, 512, nullptr, nullptr, nullptr);
  gemm_m(ah1, wtC1, c_b1, u1, 512, 768, 0, sC1, 768, nullptr, nullptr);  // u1raw + stats
  agg(u1, au, 768, sC1, c_g1, c_be1);                                    // au = agg(relu(bn(u1raw)))
  gemm_m(au, wtC2, c_b2, h2, 768, 1024, 0, sC2, 1024, nullptr, nullptr); // u2raw + stats
  gemm_m(ah1, wtC3, c_b3, h2, 512, 1024, 3, sC2, 1024, c_g2, c_be2);     // h2 = relu(bn(u2raw)) + ah1@c_w3+c_b3
  // pool + MLP (fp32)
  k_pool_b<<<NG,256,0,stream>>>(h2, startg, P);
  {
    dim3 g1(cdiv(NG,64), 1024/64);
    k_gemm<true><<<g1,256,0,stream>>>(P, mw1, mb1, Hh, NG, 1024, 1024);
    dim3 g2(cdiv(NG,64), 768/64);
    k_gemm<false><<<g2,256,0,stream>>>(Hh, mw2, mb2, out, NG, 1024, 768);
  }
}